// Round 4
// baseline (5130.166 us; speedup 1.0000x reference)
//
#include <hip/hip_runtime.h>
#include <hip/hip_bf16.h>

// ---- problem constants ----
#define BATCH   4
#define SEQL    4096
#define DMODEL  1024
#define DINNER  2048
#define NHEADS  32
#define HEADD   64
#define DSTATE  128
#define NCHUNK  64
#define CHUNK   64
#define BL      (BATCH * SEQL)          // 16384 rows
#define XDBLW   (NHEADS + 2 * DSTATE)   // 288

typedef __hip_bfloat16 bf16;

__device__ __forceinline__ float silu_f(float x) {
    return x / (1.f + expf(-x));
}
__device__ __forceinline__ float toF(float x) { return x; }
__device__ __forceinline__ float toF(bf16 x)  { return __bfloat162float(x); }
__device__ __forceinline__ void stF(float* p, float v) { *p = v; }
__device__ __forceinline__ void stF(bf16* p, float v)  { *p = __float2bfloat16(v); }

// ------------------------------------------------------------------
// Guarded SGEMM (f32 math, templated storage): C[M,N] = A[M,K] @ B[K,N(ldb)]
// 128x128 tile, BK=16, 256 threads, 8x8 per thread.
// ------------------------------------------------------------------
#define GBM 128
#define GBN 128
#define GBK 16

template <typename TA, typename TB, typename TC>
__global__ __launch_bounds__(256) void sgemm_t(
    const TA* __restrict__ A, const TB* __restrict__ B,
    TC* __restrict__ C, int M, int N, int K, int ldb)
{
    __shared__ float As[GBK][GBM + 4];
    __shared__ float Bs[GBK][GBN + 4];
    const int tid = threadIdx.x;
    const int m0 = blockIdx.y * GBM;
    const int n0 = blockIdx.x * GBN;
    const int tx = tid & 15;
    const int ty = tid >> 4;

    const int mA = tid >> 1;          // 0..127
    const int kA = (tid & 1) * 8;     // 0 or 8
    const int kB = tid >> 4;          // 0..15
    const int nB = (tid & 15) * 8;    // 0..120

    float acc[8][8] = {};

    for (int k0 = 0; k0 < K; k0 += GBK) {
        float va[8], vb[8];
        {
            const int gm = m0 + mA;
            const bool mok = gm < M;
            const size_t abase = (size_t)gm * K + (k0 + kA);
            #pragma unroll
            for (int i = 0; i < 8; i++) {
                const int gk = k0 + kA + i;
                va[i] = (mok && gk < K) ? toF(A[abase + i]) : 0.f;
            }
            const int gk = k0 + kB;
            const bool kok = gk < K;
            const size_t bbase = (size_t)gk * ldb + (n0 + nB);
            #pragma unroll
            for (int i = 0; i < 8; i++) {
                const int gn = n0 + nB + i;
                vb[i] = (kok && gn < N) ? toF(B[bbase + i]) : 0.f;
            }
        }
        __syncthreads();   // previous iteration's LDS reads complete
        #pragma unroll
        for (int i = 0; i < 8; i++) As[kA + i][mA] = va[i];
        #pragma unroll
        for (int i = 0; i < 8; i++) Bs[kB][nB + i] = vb[i];
        __syncthreads();

        #pragma unroll
        for (int kk = 0; kk < GBK; kk++) {
            float ar[8], br[8];
            const float4 a0 = *(const float4*)&As[kk][ty * 8];
            const float4 a1 = *(const float4*)&As[kk][ty * 8 + 4];
            const float4 b0 = *(const float4*)&Bs[kk][tx * 8];
            const float4 b1 = *(const float4*)&Bs[kk][tx * 8 + 4];
            ar[0]=a0.x; ar[1]=a0.y; ar[2]=a0.z; ar[3]=a0.w;
            ar[4]=a1.x; ar[5]=a1.y; ar[6]=a1.z; ar[7]=a1.w;
            br[0]=b0.x; br[1]=b0.y; br[2]=b0.z; br[3]=b0.w;
            br[4]=b1.x; br[5]=b1.y; br[6]=b1.z; br[7]=b1.w;
            #pragma unroll
            for (int i = 0; i < 8; i++)
                #pragma unroll
                for (int j = 0; j < 8; j++)
                    acc[i][j] = fmaf(ar[i], br[j], acc[i][j]);
        }
    }

    #pragma unroll
    for (int i = 0; i < 8; i++) {
        const int gm = m0 + ty * 8 + i;
        if (gm >= M) continue;
        #pragma unroll
        for (int j = 0; j < 8; j++) {
            const int gn = n0 + tx * 8 + j;
            if (gn < N) stF(&C[(size_t)gm * N + gn], acc[i][j]);
        }
    }
}

// ------------------------------------------------------------------
// Depthwise conv (window 4, SAME pad (1,2), cross-correlation) + SiLU
// for a single DINNER-wide tensor.
// ------------------------------------------------------------------
__global__ __launch_bounds__(256) void conv_one_kernel(
    const bf16* __restrict__ in,
    const float* __restrict__ k, const float* __restrict__ bias,
    bf16* __restrict__ out)
{
    const size_t idx = (size_t)blockIdx.x * 256 + threadIdx.x;
    if (idx >= (size_t)BL * DINNER) return;
    const int d = (int)(idx & (DINNER - 1));
    const size_t row = idx >> 11;               // / DINNER
    const int l = (int)(row & (SEQL - 1));
    const size_t bL = row - l;                  // b * SEQL
    float a = bias[d];
    #pragma unroll
    for (int w = 0; w < 4; w++) {
        const int ls = l + w - 1;
        if (ls >= 0 && ls < SEQL)
            a = fmaf(toF(in[(bL + ls) * (size_t)DINNER + d]), k[w * DINNER + d], a);
    }
    stF(&out[idx], silu_f(a));
}

// ------------------------------------------------------------------
// dt = softplus(x_dbl[:, :32] + dt_bias); dA = -exp(A_log)*dt;
// per-(b,c,h) inclusive cumsum of dA (64-lane wave scan); chunk totals.
// ------------------------------------------------------------------
__global__ __launch_bounds__(256) void dt_kernel(
    const float* __restrict__ x_dbl,
    const float* __restrict__ dt_bias, const float* __restrict__ A_log,
    float* __restrict__ dtb, float* __restrict__ dacs, float* __restrict__ ctot)
{
    const int bid = blockIdx.x;        // (b*NCHUNK + c)*8 + hg
    const int hg = bid & 7;
    const int bc = bid >> 3;
    const int c = bc & (NCHUNK - 1);
    const int b = bc >> 6;
    const int w = threadIdx.x >> 6, lane = threadIdx.x & 63;
    const int h = hg * 4 + w;
    const size_t row = (size_t)b * SEQL + c * CHUNK + lane;

    const float raw = x_dbl[row * XDBLW + h] + dt_bias[h];
    const float dt = (raw > 20.f) ? raw : log1pf(expf(raw));
    dtb[row * NHEADS + h] = dt;

    float s = -expf(A_log[h]) * dt;
    #pragma unroll
    for (int off = 1; off < 64; off <<= 1) {
        const float t = __shfl_up(s, off);
        if (lane >= off) s += t;
    }
    dacs[row * NHEADS + h] = s;
    if (lane == 63) ctot[((size_t)b * NHEADS + h) * NCHUNK + c] = s;
}

// ------------------------------------------------------------------
// Per (b,c,h): scores = C·B^T, L-mask, Y_diag = (scores∘L·dt)·x + D·u → y
// ------------------------------------------------------------------
__global__ __launch_bounds__(256) void ssd_diag_kernel(
    const bf16* __restrict__ u,
    const float* __restrict__ x_dbl,
    const float* __restrict__ dtb,
    const float* __restrict__ dacs,
    const float* __restrict__ Dv,
    bf16* __restrict__ y)
{
    __shared__ float CS[64 * 64];       // C-half during scores, S after
    __shared__ float Bsm[64][65];
    __shared__ float xu[64][64];
    __shared__ float csA[64], dtl[64];

    const int h = blockIdx.x, c = blockIdx.y, b = blockIdx.z;
    const int tid = threadIdx.x;
    const int lane = tid & 63, w = tid >> 6;
    const size_t row0 = (size_t)b * SEQL + c * CHUNK;

    // stage u-tile, cumsums, dt
    #pragma unroll
    for (int j = 0; j < 16; j++) {
        const int f = j * 256 + tid;
        const int l = f >> 6, p = f & 63;
        xu[l][p] = toF(u[(row0 + l) * DINNER + h * HEADD + p]);
    }
    if (tid < 64) {
        csA[tid] = dacs[(row0 + tid) * NHEADS + h];
        dtl[tid] = dtb[(row0 + tid) * NHEADS + h];
    }

    float sreg[16];
    #pragma unroll
    for (int j = 0; j < 16; j++) sreg[j] = 0.f;

    for (int half = 0; half < 2; half++) {
        const int noff = half * 64;
        __syncthreads();  // prior-phase LDS reads done before restage
        #pragma unroll
        for (int j = 0; j < 16; j++) {
            const int f = j * 256 + tid;
            const int l = f >> 6, n = f & 63;
            CS[l * 64 + n] = x_dbl[(row0 + l) * XDBLW + NHEADS + DSTATE + noff + n];
            Bsm[l][n]      = x_dbl[(row0 + l) * XDBLW + NHEADS + noff + n];
        }
        __syncthreads();
        // scores partial: thread holds S[l = si*4+w][s = lane]
        #pragma unroll
        for (int si = 0; si < 16; si++) {
            const int l = si * 4 + w;
            float a = 0.f;
            #pragma unroll 16
            for (int n = 0; n < 64; n++)
                a = fmaf(CS[l * 64 + n], Bsm[lane][n], a);
            sreg[si] += a;
        }
    }
    __syncthreads();
    // finalize S into CS: mask, decay, fold dt[s]
    #pragma unroll
    for (int si = 0; si < 16; si++) {
        const int l = si * 4 + w, s = lane;
        float v = 0.f;
        if (l >= s) v = sreg[si] * expf(csA[l] - csA[s]) * dtl[s];
        CS[l * 64 + s] = v;
    }
    __syncthreads();
    // Y_diag + D*u → y
    const float Dh = Dv[h];
    #pragma unroll
    for (int j = 0; j < 16; j++) {
        const int f = j * 256 + tid;
        const int l = f >> 6, p = f & 63;
        float a = Dh * xu[l][p];
        #pragma unroll 16
        for (int s = 0; s < 64; s++)
            a = fmaf(CS[l * 64 + s], xu[s][p], a);
        stF(&y[(row0 + l) * DINNER + h * HEADD + p], a);
    }
}

// ------------------------------------------------------------------
// Fused inter-chunk scan + Y_off.  Block = (ps, h, b); ps = p-half.
// Running state kept in registers: thread (pg=tid>>5, ng=tid&31) owns
// state[p = ps*32 + pg*4 + pp][n = ng*4 + nn], pp,nn in 0..3.
// Per chunk c: (A) y += exp(cs[l]) * C · prev^T   (prev = run, skip c=0)
//              (B) run = run*exp(ctot[c]) + x^T · (B·decay·dt)
// ------------------------------------------------------------------
__global__ __launch_bounds__(256) void ssd_scan_off_kernel(
    const bf16* __restrict__ u,
    const float* __restrict__ x_dbl,
    const float* __restrict__ dtb,
    const float* __restrict__ dacs,
    const float* __restrict__ ctot,
    bf16* __restrict__ y)
{
    __shared__ float CB[64][132];   // C (phase A) then B-scaled (phase B)
    __shared__ float pv[32][132];   // prev-state staging
    __shared__ float xs[64][36];    // u tile (this p-half)
    __shared__ float eC[64], eD[64], csL[64], dtL[64];

    const int ps = blockIdx.x, h = blockIdx.y, b = blockIdx.z;
    const int tid = threadIdx.x;
    const int pg = tid >> 5;        // 0..7
    const int ng = tid & 31;        // 0..31
    const int po2 = tid & 15;       // phase-A output p-pair
    const int lg  = tid >> 4;       // phase-A output l-quad

    float run[4][4];
    #pragma unroll
    for (int i = 0; i < 4; i++)
        #pragma unroll
        for (int j = 0; j < 4; j++) run[i][j] = 0.f;

    const float* ct = ctot + ((size_t)b * NHEADS + h) * NCHUNK;
    const int pcol = h * HEADD + ps * 32;

    for (int c = 0; c < NCHUNK; c++) {
        const size_t row0 = (size_t)b * SEQL + c * CHUNK;
        if (tid < 64) {
            csL[tid] = dacs[(row0 + tid) * NHEADS + h];
            dtL[tid] = dtb[(row0 + tid) * NHEADS + h];
        }
        __syncthreads();            // csL visible; prev chunk's update done
        if (tid < 64) {
            eC[tid] = expf(csL[tid]);
            eD[tid] = expf(csL[63] - csL[tid]) * dtL[tid];
        }
        __syncthreads();            // eC/eD visible; CB free to overwrite

        if (c > 0) {
            // phase A: stage C and prev, accumulate Y_off
            #pragma unroll
            for (int k = 0; k < 32; k++) {
                const int f = k * 256 + tid;
                const int l = f >> 7, n = f & 127;
                CB[l][n] = x_dbl[(row0 + l) * XDBLW + NHEADS + DSTATE + n];
            }
            #pragma unroll
            for (int pp = 0; pp < 4; pp++)
                *(float4*)&pv[pg * 4 + pp][ng * 4] =
                    make_float4(run[pp][0], run[pp][1], run[pp][2], run[pp][3]);
            __syncthreads();

            float acc[4][2] = {};
            #pragma unroll
            for (int nq = 0; nq < 32; nq++) {
                const float4 p0 = *(const float4*)&pv[po2 * 2][nq * 4];
                const float4 p1 = *(const float4*)&pv[po2 * 2 + 1][nq * 4];
                #pragma unroll
                for (int i = 0; i < 4; i++) {
                    const float4 cv = *(const float4*)&CB[lg * 4 + i][nq * 4];
                    acc[i][0] = fmaf(cv.x, p0.x, fmaf(cv.y, p0.y,
                                fmaf(cv.z, p0.z, fmaf(cv.w, p0.w, acc[i][0]))));
                    acc[i][1] = fmaf(cv.x, p1.x, fmaf(cv.y, p1.y,
                                fmaf(cv.z, p1.z, fmaf(cv.w, p1.w, acc[i][1]))));
                }
            }
            #pragma unroll
            for (int i = 0; i < 4; i++) {
                const int l = lg * 4 + i;
                const float e = eC[l];
                #pragma unroll
                for (int jj = 0; jj < 2; jj++) {
                    const size_t yi = (row0 + l) * DINNER + pcol + po2 * 2 + jj;
                    stF(&y[yi], toF(y[yi]) + e * acc[i][jj]);
                }
            }
            __syncthreads();        // done reading CB before restage
        }

        // phase B: stage B·decay·dt and u-tile, update running state
        #pragma unroll
        for (int k = 0; k < 32; k++) {
            const int f = k * 256 + tid;
            const int l = f >> 7, n = f & 127;
            CB[l][n] = x_dbl[(row0 + l) * XDBLW + NHEADS + n] * eD[l];
        }
        #pragma unroll
        for (int k = 0; k < 8; k++) {
            const int f = k * 256 + tid;
            const int l = f >> 5, p = f & 31;
            xs[l][p] = toF(u[(row0 + l) * DINNER + pcol + p]);
        }
        __syncthreads();

        const float dc = expf(ct[c]);
        #pragma unroll
        for (int i = 0; i < 4; i++)
            #pragma unroll
            for (int j = 0; j < 4; j++) run[i][j] *= dc;
        #pragma unroll 8
        for (int l = 0; l < 64; l++) {
            const float4 xv = *(const float4*)&xs[l][pg * 4];
            const float4 bv = *(const float4*)&CB[l][ng * 4];
            run[0][0] = fmaf(xv.x, bv.x, run[0][0]);
            run[0][1] = fmaf(xv.x, bv.y, run[0][1]);
            run[0][2] = fmaf(xv.x, bv.z, run[0][2]);
            run[0][3] = fmaf(xv.x, bv.w, run[0][3]);
            run[1][0] = fmaf(xv.y, bv.x, run[1][0]);
            run[1][1] = fmaf(xv.y, bv.y, run[1][1]);
            run[1][2] = fmaf(xv.y, bv.z, run[1][2]);
            run[1][3] = fmaf(xv.y, bv.w, run[1][3]);
            run[2][0] = fmaf(xv.z, bv.x, run[2][0]);
            run[2][1] = fmaf(xv.z, bv.y, run[2][1]);
            run[2][2] = fmaf(xv.z, bv.z, run[2][2]);
            run[2][3] = fmaf(xv.z, bv.w, run[2][3]);
            run[3][0] = fmaf(xv.w, bv.x, run[3][0]);
            run[3][1] = fmaf(xv.w, bv.y, run[3][1]);
            run[3][2] = fmaf(xv.w, bv.z, run[3][2]);
            run[3][3] = fmaf(xv.w, bv.w, run[3][3]);
        }
        // loop-top barrier closes the chunk
    }
}

// ------------------------------------------------------------------
// y = y * silu(z); RMS-norm over DINNER; * norm_w.  In place on y.
// ------------------------------------------------------------------
__global__ __launch_bounds__(256) void gate_norm_kernel(
    bf16* __restrict__ y, const bf16* __restrict__ z,
    const float* __restrict__ norm_w)
{
    __shared__ float red[4];
    const size_t row = blockIdx.x;
    const int tid = threadIdx.x;
    float v[8];
    float ss = 0.f;
    #pragma unroll
    for (int j = 0; j < 8; j++) {
        const size_t i = row * DINNER + j * 256 + tid;
        const float val = toF(y[i]) * silu_f(toF(z[i]));
        v[j] = val;
        ss = fmaf(val, val, ss);
    }
    #pragma unroll
    for (int off = 32; off > 0; off >>= 1) ss += __shfl_down(ss, off);
    const int lane = tid & 63, w = tid >> 6;
    if (lane == 0) red[w] = ss;
    __syncthreads();
    const float tot = red[0] + red[1] + red[2] + red[3];
    const float scale = rsqrtf(tot / (float)DINNER + 1e-6f);
    #pragma unroll
    for (int j = 0; j < 8; j++) {
        const size_t i = row * DINNER + j * 256 + tid;
        stF(&y[i], v[j] * scale * norm_w[j * 256 + tid]);
    }
}

// ------------------------------------------------------------------
extern "C" void kernel_launch(void* const* d_in, const int* in_sizes, int n_in,
                              void* d_out, int out_size, void* d_ws, size_t ws_size,
                              hipStream_t stream)
{
    const float* x       = (const float*)d_in[0];
    const float* W_in    = (const float*)d_in[1];
    const float* conv_xk = (const float*)d_in[2];
    const float* conv_xb = (const float*)d_in[3];
    const float* conv_zk = (const float*)d_in[4];
    const float* conv_zb = (const float*)d_in[5];
    const float* W_x     = (const float*)d_in[6];
    const float* dt_bias = (const float*)d_in[7];
    const float* A_log   = (const float*)d_in[8];
    const float* Dv      = (const float*)d_in[9];
    const float* norm_w  = (const float*)d_in[10];
    const float* W_out   = (const float*)d_in[11];
    float* out = (float*)d_out;
    char* ws   = (char*)d_ws;

    // workspace layout (bytes), peak 224,428,032 (~214 MB):
    //  u:      [0,            67,108,864)   bf16
    //  z:      [67,108,864,   134,217,728)  bf16
    //  S:      [134,217,728,  201,326,592)  bf16 scratch: zpre -> upre -> y
    //  x_dbl:  [201,326,592,  220,200,960)  f32
    //  dtb:    [220,200,960,  222,298,112)  f32
    //  dacs:   [222,298,112,  224,395,264)  f32
    //  ctot:   [224,395,264,  224,428,032)  f32
    if (ws_size < (size_t)224428032) return;   // diagnostic guard
    bf16*  u      = (bf16*)(ws);
    bf16*  z      = (bf16*)(ws + 67108864);
    bf16*  scr    = (bf16*)(ws + 134217728);   // zpre / upre / y
    float* x_dbl  = (float*)(ws + 201326592);
    float* dtb    = (float*)(ws + 220200960);
    float* dacs   = (float*)(ws + 222298112);
    float* ctot   = (float*)(ws + 224395264);
    bf16* y = scr;

    // 1a. zpre = x @ W_in[:, 2048:4096] → scr
    sgemm_t<float, float, bf16><<<dim3(DINNER / GBN, BL / GBM), 256, 0, stream>>>(
        x, W_in + DINNER, scr, BL, DINNER, DMODEL, 2 * DINNER);
    // 1b. z = silu(conv(zpre))
    conv_one_kernel<<<(BL * DINNER) / 256, 256, 0, stream>>>(scr, conv_zk, conv_zb, z);
    // 2a. upre = x @ W_in[:, 0:2048] → scr (zpre dead)
    sgemm_t<float, float, bf16><<<dim3(DINNER / GBN, BL / GBM), 256, 0, stream>>>(
        x, W_in, scr, BL, DINNER, DMODEL, 2 * DINNER);
    // 2b. u = silu(conv(upre))
    conv_one_kernel<<<(BL * DINNER) / 256, 256, 0, stream>>>(scr, conv_xk, conv_xb, u);
    // 3. x_dbl = u @ W_x
    sgemm_t<bf16, float, float><<<dim3((XDBLW + GBN - 1) / GBN, BL / GBM), 256, 0, stream>>>(
        u, W_x, x_dbl, BL, XDBLW, DINNER, XDBLW);
    // 4. dt / dA cumsums
    dt_kernel<<<BATCH * NCHUNK * 8, 256, 0, stream>>>(
        x_dbl, dt_bias, A_log, dtb, dacs, ctot);
    // 5. intra-chunk Y_diag → y (scr; upre dead)
    ssd_diag_kernel<<<dim3(NHEADS, NCHUNK, BATCH), 256, 0, stream>>>(
        u, x_dbl, dtb, dacs, Dv, y);
    // 6. fused inter-chunk scan + Y_off accumulate into y
    ssd_scan_off_kernel<<<dim3(2, NHEADS, BATCH), 256, 0, stream>>>(
        u, x_dbl, dtb, dacs, ctot, y);
    // 7. gate + RMS norm (in place on y)
    gate_norm_kernel<<<BL, 256, 0, stream>>>(y, z, norm_w);
    // 8. out = y @ W_out
    sgemm_t<bf16, float, float><<<dim3(DMODEL / GBN, BL / GBM), 256, 0, stream>>>(
        y, W_out, out, BL, DMODEL, DINNER, DMODEL);
}

// Round 7
// 2059.096 us; speedup vs baseline: 2.4915x; 2.4915x over previous
//
#include <hip/hip_runtime.h>
#include <hip/hip_bf16.h>

// ---- problem constants ----
#define BATCH   4
#define SEQL    4096
#define DMODEL  1024
#define DINNER  2048
#define NHEADS  32
#define HEADD   64
#define DSTATE  128
#define NCHUNK  64
#define CHUNK   64
#define BL      (BATCH * SEQL)          // 16384 rows
#define XDBLW   (NHEADS + 2 * DSTATE)   // 288

typedef __hip_bfloat16 bf16;
typedef __attribute__((ext_vector_type(8))) short s16x8;
typedef __attribute__((ext_vector_type(8))) unsigned short u16x8;
typedef __attribute__((ext_vector_type(4))) float f32x4;

__device__ __forceinline__ float silu_f(float x) {
    return x / (1.f + expf(-x));
}
__device__ __forceinline__ float toF(float x) { return x; }
__device__ __forceinline__ float toF(bf16 x)  { return __bfloat162float(x); }
__device__ __forceinline__ void stF(float* p, float v) { *p = v; }
__device__ __forceinline__ void stF(bf16* p, float v)  { *p = __float2bfloat16(v); }
__device__ __forceinline__ float bfbits2f(unsigned short b) {
    unsigned int u = ((unsigned int)b) << 16;
    return __builtin_bit_cast(float, u);
}

// ------------------------------------------------------------------
// f32 -> bf16 bulk convert (4 per thread)
// ------------------------------------------------------------------
__global__ __launch_bounds__(256) void f32_to_bf16_kernel(
    const float* __restrict__ in, bf16* __restrict__ out, size_t n)
{
    const size_t i = ((size_t)blockIdx.x * 256 + threadIdx.x) * 4;
    if (i >= n) return;
    const float4 v = *(const float4*)(in + i);
    bf16 o[4];
    o[0] = __float2bfloat16(v.x); o[1] = __float2bfloat16(v.y);
    o[2] = __float2bfloat16(v.z); o[3] = __float2bfloat16(v.w);
    __builtin_memcpy(&out[i], o, 8);
}

// ------------------------------------------------------------------
// Transpose f32 [R][C] -> bf16 [Cpad][R], zero-pad rows c >= C.
// grid (Cpad/32, R/32), 256 threads.
// ------------------------------------------------------------------
__global__ __launch_bounds__(256) void transpose_to_bf16_kernel(
    const float* __restrict__ in, bf16* __restrict__ out,
    int R, int C, int Cpad)
{
    __shared__ float t[32][33];
    const int c0 = blockIdx.x * 32, r0 = blockIdx.y * 32;
    const int tx = threadIdx.x & 31, ty = threadIdx.x >> 5;  // ty 0..7
    #pragma unroll
    for (int i = 0; i < 4; i++) {
        const int r = r0 + ty + i * 8, c = c0 + tx;
        t[ty + i * 8][tx] = (c < C) ? in[(size_t)r * C + c] : 0.f;
    }
    __syncthreads();
    #pragma unroll
    for (int i = 0; i < 4; i++) {
        const int c = c0 + ty + i * 8, r = r0 + tx;
        out[(size_t)c * R + r] = __float2bfloat16(t[tx][ty + i * 8]);
    }
}

// ------------------------------------------------------------------
// MFMA bf16 GEMM: C[M,N] = A[M,K] x Bt[N,K]^T  (Bt row n = column n of B)
// 128x128 tile, BK=32, 4 waves (each 64x64 = 4x4 16x16 frags), f32 acc.
// LDS layout [ko4][row][8 bf16] -> conflict-free ds_read_b128, linear
// global_load_lds staging. M, K multiples of 128/32; N guarded by Nout.
// ------------------------------------------------------------------
template <typename TC>
__global__ __launch_bounds__(256) void mfma_gemm(
    const bf16* __restrict__ A, const bf16* __restrict__ Bt,
    TC* __restrict__ C, int M, int Nout, int K, int lda, int ldb, int ldc)
{
    __shared__ __align__(16) bf16 As[4096];   // [4][128][8]
    __shared__ __align__(16) bf16 Bs[4096];
    const int tid = threadIdx.x;
    const int m0 = blockIdx.y * 128;
    const int n0 = blockIdx.x * 128;
    const int wave = tid >> 6, lane = tid & 63;
    const int wr = wave >> 1, wc = wave & 1;   // wave quadrant (wr*64, wc*64)
    const int fr = lane & 15;
    const int fq = lane >> 4;

    f32x4 acc[4][4];
    #pragma unroll
    for (int i = 0; i < 4; i++)
        #pragma unroll
        for (int j = 0; j < 4; j++)
            acc[i][j] = (f32x4){0.f, 0.f, 0.f, 0.f};

    // staging: thread t covers tile row (t&127), k-offset (t>>7)*8 (+issue*16)
    const int srow = tid & 127;
    const int sk0 = (tid >> 7) * 8;
    const bf16* Ag = A + (size_t)(m0 + srow) * lda + sk0;
    const bf16* Bg = Bt + (size_t)(n0 + srow) * ldb + sk0;
    const int lb = (wave >> 1) * 1024 + (wave & 1) * 512;  // wave-uniform elems

    for (int k0 = 0; k0 < K; k0 += 32) {
        __syncthreads();   // previous iteration's LDS reads complete
        #pragma unroll
        for (int i = 0; i < 2; i++) {
            __builtin_amdgcn_global_load_lds(
                (const __attribute__((address_space(1))) unsigned int*)(Ag + k0 + i * 16),
                (__attribute__((address_space(3))) unsigned int*)(As + i * 2048 + lb),
                16, 0, 0);
            __builtin_amdgcn_global_load_lds(
                (const __attribute__((address_space(1))) unsigned int*)(Bg + k0 + i * 16),
                (__attribute__((address_space(3))) unsigned int*)(Bs + i * 2048 + lb),
                16, 0, 0);
        }
        __syncthreads();   // staging complete (compiler drains vmcnt)

        s16x8 af[4], bfv[4];
        #pragma unroll
        for (int mi = 0; mi < 4; mi++)
            af[mi] = *(const s16x8*)&As[fq * 1024 + (wr * 64 + mi * 16 + fr) * 8];
        #pragma unroll
        for (int ni = 0; ni < 4; ni++)
            bfv[ni] = *(const s16x8*)&Bs[fq * 1024 + (wc * 64 + ni * 16 + fr) * 8];
        #pragma unroll
        for (int mi = 0; mi < 4; mi++)
            #pragma unroll
            for (int ni = 0; ni < 4; ni++)
                acc[mi][ni] = __builtin_amdgcn_mfma_f32_16x16x32_bf16(
                    af[mi], bfv[ni], acc[mi][ni], 0, 0, 0);
    }

    #pragma unroll
    for (int mi = 0; mi < 4; mi++) {
        #pragma unroll
        for (int ni = 0; ni < 4; ni++) {
            const int col = n0 + wc * 64 + ni * 16 + fr;
            if (col < Nout) {
                #pragma unroll
                for (int r = 0; r < 4; r++) {
                    const int row = m0 + wr * 64 + mi * 16 + fq * 4 + r;
                    stF(&C[(size_t)row * ldc + col], acc[mi][ni][r]);
                }
            }
        }
    }
}

// ------------------------------------------------------------------
// Depthwise conv (window 4, SAME pad (1,2), cross-correlation) + SiLU.
// Vectorized: 8 consecutive channels per thread, 16B loads/stores.
// ------------------------------------------------------------------
__global__ __launch_bounds__(256) void conv_one_kernel(
    const bf16* __restrict__ in,
    const float* __restrict__ kern, const float* __restrict__ bias,
    bf16* __restrict__ out)
{
    const size_t gid = (size_t)blockIdx.x * 256 + threadIdx.x;
    const int d0 = ((int)(gid & 255)) << 3;
    const size_t row = gid >> 8;
    const int l = (int)(row & (SEQL - 1));
    const size_t bL = row - l;
    float a[8];
    #pragma unroll
    for (int j = 0; j < 8; j++) a[j] = bias[d0 + j];
    #pragma unroll
    for (int w = 0; w < 4; w++) {
        const int ls = l + w - 1;
        if (ls >= 0 && ls < SEQL) {
            u16x8 v;
            __builtin_memcpy(&v, &in[(bL + ls) * DINNER + d0], 16);
            #pragma unroll
            for (int j = 0; j < 8; j++)
                a[j] = fmaf(bfbits2f(v[j]), kern[w * DINNER + d0 + j], a[j]);
        }
    }
    bf16 ov[8];
    #pragma unroll
    for (int j = 0; j < 8; j++) ov[j] = __float2bfloat16(silu_f(a[j]));
    __builtin_memcpy(&out[row * DINNER + d0], ov, 16);
}

// ------------------------------------------------------------------
// dt = softplus(x_dbl[:, :32] + dt_bias); dA = -exp(A_log)*dt;
// per-(b,c,h) inclusive cumsum of dA (64-lane wave scan); chunk totals.
// ------------------------------------------------------------------
__global__ __launch_bounds__(256) void dt_kernel(
    const float* __restrict__ x_dbl,
    const float* __restrict__ dt_bias, const float* __restrict__ A_log,
    float* __restrict__ dtb, float* __restrict__ dacs, float* __restrict__ ctot)
{
    const int bid = blockIdx.x;        // (b*NCHUNK + c)*8 + hg
    const int hg = bid & 7;
    const int bc = bid >> 3;
    const int c = bc & (NCHUNK - 1);
    const int b = bc >> 6;
    const int w = threadIdx.x >> 6, lane = threadIdx.x & 63;
    const int h = hg * 4 + w;
    const size_t row = (size_t)b * SEQL + c * CHUNK + lane;

    const float raw = x_dbl[row * XDBLW + h] + dt_bias[h];
    const float dt = (raw > 20.f) ? raw : log1pf(expf(raw));
    dtb[row * NHEADS + h] = dt;

    float s = -expf(A_log[h]) * dt;
    #pragma unroll
    for (int off = 1; off < 64; off <<= 1) {
        const float t = __shfl_up(s, off);
        if (lane >= off) s += t;
    }
    dacs[row * NHEADS + h] = s;
    if (lane == 63) ctot[((size_t)b * NHEADS + h) * NCHUNK + c] = s;
}

// ------------------------------------------------------------------
// Per (b,c,h): scores = C·B^T, L-mask, Y_diag = (scores∘L·dt)·x + D·u → y
// ------------------------------------------------------------------
__global__ __launch_bounds__(256) void ssd_diag_kernel(
    const bf16* __restrict__ u,
    const float* __restrict__ x_dbl,
    const float* __restrict__ dtb,
    const float* __restrict__ dacs,
    const float* __restrict__ Dv,
    bf16* __restrict__ y)
{
    __shared__ float CS[64 * 64];       // C-half during scores, S after
    __shared__ float Bsm[64][65];
    __shared__ float xu[64][64];
    __shared__ float csA[64], dtl[64];

    const int h = blockIdx.x, c = blockIdx.y, b = blockIdx.z;
    const int tid = threadIdx.x;
    const int lane = tid & 63, w = tid >> 6;
    const size_t row0 = (size_t)b * SEQL + c * CHUNK;

    // stage u-tile, cumsums, dt
    #pragma unroll
    for (int j = 0; j < 16; j++) {
        const int f = j * 256 + tid;
        const int l = f >> 6, p = f & 63;
        xu[l][p] = toF(u[(row0 + l) * DINNER + h * HEADD + p]);
    }
    if (tid < 64) {
        csA[tid] = dacs[(row0 + tid) * NHEADS + h];
        dtl[tid] = dtb[(row0 + tid) * NHEADS + h];
    }

    float sreg[16];
    #pragma unroll
    for (int j = 0; j < 16; j++) sreg[j] = 0.f;

    for (int half = 0; half < 2; half++) {
        const int noff = half * 64;
        __syncthreads();  // prior-phase LDS reads done before restage
        #pragma unroll
        for (int j = 0; j < 16; j++) {
            const int f = j * 256 + tid;
            const int l = f >> 6, n = f & 63;
            CS[l * 64 + n] = x_dbl[(row0 + l) * XDBLW + NHEADS + DSTATE + noff + n];
            Bsm[l][n]      = x_dbl[(row0 + l) * XDBLW + NHEADS + noff + n];
        }
        __syncthreads();
        // scores partial: thread holds S[l = si*4+w][s = lane]
        #pragma unroll
        for (int si = 0; si < 16; si++) {
            const int l = si * 4 + w;
            float a = 0.f;
            #pragma unroll 16
            for (int n = 0; n < 64; n++)
                a = fmaf(CS[l * 64 + n], Bsm[lane][n], a);
            sreg[si] += a;
        }
    }
    __syncthreads();
    // finalize S into CS: mask, decay, fold dt[s]
    #pragma unroll
    for (int si = 0; si < 16; si++) {
        const int l = si * 4 + w, s = lane;
        float v = 0.f;
        if (l >= s) v = sreg[si] * expf(csA[l] - csA[s]) * dtl[s];
        CS[l * 64 + s] = v;
    }
    __syncthreads();
    // Y_diag + D*u → y
    const float Dh = Dv[h];
    #pragma unroll
    for (int j = 0; j < 16; j++) {
        const int f = j * 256 + tid;
        const int l = f >> 6, p = f & 63;
        float a = Dh * xu[l][p];
        #pragma unroll 16
        for (int s = 0; s < 64; s++)
            a = fmaf(CS[l * 64 + s], xu[s][p], a);
        stF(&y[(row0 + l) * DINNER + h * HEADD + p], a);
    }
}

// ------------------------------------------------------------------
// Fused inter-chunk scan + Y_off.  Block = (ps, h, b); ps = p-half.
// Per chunk c: (A) y += exp(cs[l]) * C · prev^T  (prev = run, skip c=0)
//              (B) run = run*exp(ctot[c]) + x^T · (B·decay·dt)
// ------------------------------------------------------------------
__global__ __launch_bounds__(256) void ssd_scan_off_kernel(
    const bf16* __restrict__ u,
    const float* __restrict__ x_dbl,
    const float* __restrict__ dtb,
    const float* __restrict__ dacs,
    const float* __restrict__ ctot,
    bf16* __restrict__ y)
{
    __shared__ float CB[64][132];   // C (phase A) then B-scaled (phase B)
    __shared__ float pv[32][132];   // prev-state staging
    __shared__ float xs[64][36];    // u tile (this p-half)
    __shared__ float eC[64], eD[64], csL[64], dtL[64];

    const int ps = blockIdx.x, h = blockIdx.y, b = blockIdx.z;
    const int tid = threadIdx.x;
    const int pg = tid >> 5;        // 0..7
    const int ng = tid & 31;        // 0..31
    const int po2 = tid & 15;       // phase-A output p-pair
    const int lg  = tid >> 4;       // phase-A output l-quad

    float run[4][4];
    #pragma unroll
    for (int i = 0; i < 4; i++)
        #pragma unroll
        for (int j = 0; j < 4; j++) run[i][j] = 0.f;

    const float* ct = ctot + ((size_t)b * NHEADS + h) * NCHUNK;
    const int pcol = h * HEADD + ps * 32;

    for (int c = 0; c < NCHUNK; c++) {
        const size_t row0 = (size_t)b * SEQL + c * CHUNK;
        if (tid < 64) {
            csL[tid] = dacs[(row0 + tid) * NHEADS + h];
            dtL[tid] = dtb[(row0 + tid) * NHEADS + h];
        }
        __syncthreads();            // csL visible; prev chunk's update done
        if (tid < 64) {
            eC[tid] = expf(csL[tid]);
            eD[tid] = expf(csL[63] - csL[tid]) * dtL[tid];
        }
        __syncthreads();            // eC/eD visible; CB free to overwrite

        if (c > 0) {
            // phase A: stage C and prev, accumulate Y_off
            #pragma unroll
            for (int k = 0; k < 32; k++) {
                const int f = k * 256 + tid;
                const int l = f >> 7, n = f & 127;
                CB[l][n] = x_dbl[(row0 + l) * XDBLW + NHEADS + DSTATE + n];
            }
            #pragma unroll
            for (int pp = 0; pp < 4; pp++)
                *(float4*)&pv[pg * 4 + pp][ng * 4] =
                    make_float4(run[pp][0], run[pp][1], run[pp][2], run[pp][3]);
            __syncthreads();

            float acc[4][2] = {};
            #pragma unroll
            for (int nq = 0; nq < 32; nq++) {
                const float4 p0 = *(const float4*)&pv[po2 * 2][nq * 4];
                const float4 p1 = *(const float4*)&pv[po2 * 2 + 1][nq * 4];
                #pragma unroll
                for (int i = 0; i < 4; i++) {
                    const float4 cv = *(const float4*)&CB[lg * 4 + i][nq * 4];
                    acc[i][0] = fmaf(cv.x, p0.x, fmaf(cv.y, p0.y,
                                fmaf(cv.z, p0.z, fmaf(cv.w, p0.w, acc[i][0]))));
                    acc[i][1] = fmaf(cv.x, p1.x, fmaf(cv.y, p1.y,
                                fmaf(cv.z, p1.z, fmaf(cv.w, p1.w, acc[i][1]))));
                }
            }
            #pragma unroll
            for (int i = 0; i < 4; i++) {
                const int l = lg * 4 + i;
                const float e = eC[l];
                #pragma unroll
                for (int jj = 0; jj < 2; jj++) {
                    const size_t yi = (row0 + l) * DINNER + pcol + po2 * 2 + jj;
                    stF(&y[yi], toF(y[yi]) + e * acc[i][jj]);
                }
            }
            __syncthreads();        // done reading CB before restage
        }

        // phase B: stage B·decay·dt and u-tile, update running state
        #pragma unroll
        for (int k = 0; k < 32; k++) {
            const int f = k * 256 + tid;
            const int l = f >> 7, n = f & 127;
            CB[l][n] = x_dbl[(row0 + l) * XDBLW + NHEADS + n] * eD[l];
        }
        #pragma unroll
        for (int k = 0; k < 8; k++) {
            const int f = k * 256 + tid;
            const int l = f >> 5, p = f & 31;
            xs[l][p] = toF(u[(row0 + l) * DINNER + pcol + p]);
        }
        __syncthreads();

        const float dc = expf(ct[c]);
        #pragma unroll
        for (int i = 0; i < 4; i++)
            #pragma unroll
            for (int j = 0; j < 4; j++) run[i][j] *= dc;
        #pragma unroll 8
        for (int l = 0; l < 64; l++) {
            const float4 xv = *(const float4*)&xs[l][pg * 4];
            const float4 bv = *(const float4*)&CB[l][ng * 4];
            run[0][0] = fmaf(xv.x, bv.x, run[0][0]);
            run[0][1] = fmaf(xv.x, bv.y, run[0][1]);
            run[0][2] = fmaf(xv.x, bv.z, run[0][2]);
            run[0][3] = fmaf(xv.x, bv.w, run[0][3]);
            run[1][0] = fmaf(xv.y, bv.x, run[1][0]);
            run[1][1] = fmaf(xv.y, bv.y, run[1][1]);
            run[1][2] = fmaf(xv.y, bv.z, run[1][2]);
            run[1][3] = fmaf(xv.y, bv.w, run[1][3]);
            run[2][0] = fmaf(xv.z, bv.x, run[2][0]);
            run[2][1] = fmaf(xv.z, bv.y, run[2][1]);
            run[2][2] = fmaf(xv.z, bv.z, run[2][2]);
            run[2][3] = fmaf(xv.z, bv.w, run[2][3]);
            run[3][0] = fmaf(xv.w, bv.x, run[3][0]);
            run[3][1] = fmaf(xv.w, bv.y, run[3][1]);
            run[3][2] = fmaf(xv.w, bv.z, run[3][2]);
            run[3][3] = fmaf(xv.w, bv.w, run[3][3]);
        }
        // loop-top barrier closes the chunk
    }
}

// ------------------------------------------------------------------
// y = y * silu(z); RMS-norm over DINNER; * norm_w.  In place on y.
// Vectorized: 8 channels per thread (256 threads x 8 = 2048).
// ------------------------------------------------------------------
__global__ __launch_bounds__(256) void gate_norm_kernel(
    bf16* __restrict__ y, const bf16* __restrict__ z,
    const float* __restrict__ norm_w)
{
    __shared__ float red[4];
    const size_t row = blockIdx.x;
    const int tid = threadIdx.x;
    const int d0 = tid * 8;
    u16x8 yv, zv;
    __builtin_memcpy(&yv, &y[row * DINNER + d0], 16);
    __builtin_memcpy(&zv, &z[row * DINNER + d0], 16);
    float v[8];
    float ss = 0.f;
    #pragma unroll
    for (int j = 0; j < 8; j++) {
        const float val = bfbits2f(yv[j]) * silu_f(bfbits2f(zv[j]));
        v[j] = val;
        ss = fmaf(val, val, ss);
    }
    #pragma unroll
    for (int off = 32; off > 0; off >>= 1) ss += __shfl_down(ss, off);
    const int lane = tid & 63, w = tid >> 6;
    if (lane == 0) red[w] = ss;
    __syncthreads();
    const float tot = red[0] + red[1] + red[2] + red[3];
    const float scale = rsqrtf(tot / (float)DINNER + 1e-6f);
    bf16 ov[8];
    #pragma unroll
    for (int j = 0; j < 8; j++)
        ov[j] = __float2bfloat16(v[j] * scale * norm_w[d0 + j]);
    __builtin_memcpy(&y[row * DINNER + d0], ov, 16);
}

// ------------------------------------------------------------------
extern "C" void kernel_launch(void* const* d_in, const int* in_sizes, int n_in,
                              void* d_out, int out_size, void* d_ws, size_t ws_size,
                              hipStream_t stream)
{
    const float* x       = (const float*)d_in[0];
    const float* W_in    = (const float*)d_in[1];
    const float* conv_xk = (const float*)d_in[2];
    const float* conv_xb = (const float*)d_in[3];
    const float* conv_zk = (const float*)d_in[4];
    const float* conv_zb = (const float*)d_in[5];
    const float* W_x     = (const float*)d_in[6];
    const float* dt_bias = (const float*)d_in[7];
    const float* A_log   = (const float*)d_in[8];
    const float* Dv      = (const float*)d_in[9];
    const float* norm_w  = (const float*)d_in[10];
    const float* W_out   = (const float*)d_in[11];
    float* out = (float*)d_out;
    char* ws   = (char*)d_ws;

    // workspace layout (bytes), peak 230,195,200 (~220 MB):
    //  xbf:    [0,            33,554,432)   bf16 x  (dead after GEMM 2a)
    //  W_inT:  [33,554,432,   41,943,040)   bf16 [4096][1024] (dead after 2a)
    //  u:      [0,            67,108,864)   bf16 (written step 2b, over xbf/W_inT)
    //  z:      [67,108,864,   134,217,728)  bf16
    //  scr:    [134,217,728,  201,326,592)  bf16: zpre -> upre -> y
    //  x_dbl:  [201,326,592,  220,200,960)  f32
    //  dtb:    [220,200,960,  222,298,112)  f32
    //  dacs:   [222,298,112,  224,395,264)  f32
    //  ctot:   [224,395,264,  224,428,032)  f32
    //  W_xT:   [224,428,032,  226,000,896)  bf16 [384][2048] zero-padded
    //  W_outT: [226,000,896,  230,195,200)  bf16 [1024][2048]
    if (ws_size < (size_t)230195200) return;   // diagnostic guard
    bf16*  xbf    = (bf16*)(ws);
    bf16*  W_inT  = (bf16*)(ws + 33554432);
    bf16*  u      = (bf16*)(ws);
    bf16*  z      = (bf16*)(ws + 67108864);
    bf16*  scr    = (bf16*)(ws + 134217728);   // zpre / upre / y
    float* x_dbl  = (float*)(ws + 201326592);
    float* dtb    = (float*)(ws + 220200960);
    float* dacs   = (float*)(ws + 222298112);
    float* ctot   = (float*)(ws + 224395264);
    bf16*  W_xT   = (bf16*)(ws + 224428032);
    bf16*  W_outT = (bf16*)(ws + 226000896);
    bf16* y = scr;

    // 0. convert x to bf16; transpose weights to bf16 B^T layouts
    f32_to_bf16_kernel<<<16384, 256, 0, stream>>>(x, xbf, (size_t)BL * DMODEL);
    transpose_to_bf16_kernel<<<dim3(128, 32), 256, 0, stream>>>(
        W_in, W_inT, DMODEL, 2 * DINNER, 2 * DINNER);
    transpose_to_bf16_kernel<<<dim3(12, 64), 256, 0, stream>>>(
        W_x, W_xT, DINNER, XDBLW, 384);
    transpose_to_bf16_kernel<<<dim3(32, 64), 256, 0, stream>>>(
        W_out, W_outT, DINNER, DMODEL, DMODEL);

    // 1a. zpre = x @ W_in[:, 2048:4096] → scr
    mfma_gemm<bf16><<<dim3(16, 128), 256, 0, stream>>>(
        xbf, W_inT + (size_t)DINNER * DMODEL, scr, BL, DINNER, DMODEL,
        DMODEL, DMODEL, DINNER);
    // 1b. z = silu(conv(zpre))
    conv_one_kernel<<<BL, 256, 0, stream>>>(scr, conv_zk, conv_zb, z);
    // 2a. upre = x @ W_in[:, 0:2048] → scr (zpre dead)
    mfma_gemm<bf16><<<dim3(16, 128), 256, 0, stream>>>(
        xbf, W_inT, scr, BL, DINNER, DMODEL, DMODEL, DMODEL, DINNER);
    // 2b. u = silu(conv(upre))  (overwrites xbf/W_inT region — both dead)
    conv_one_kernel<<<BL, 256, 0, stream>>>(scr, conv_xk, conv_xb, u);
    // 3. x_dbl = u @ W_x
    mfma_gemm<float><<<dim3(3, 128), 256, 0, stream>>>(
        u, W_xT, x_dbl, BL, XDBLW, DINNER, DINNER, DINNER, XDBLW);
    // 4. dt / dA cumsums
    dt_kernel<<<BATCH * NCHUNK * 8, 256, 0, stream>>>(
        x_dbl, dt_bias, A_log, dtb, dacs, ctot);
    // 5. intra-chunk Y_diag → y (scr; upre dead)
    ssd_diag_kernel<<<dim3(NHEADS, NCHUNK, BATCH), 256, 0, stream>>>(
        u, x_dbl, dtb, dacs, Dv, y);
    // 6. fused inter-chunk scan + Y_off accumulate into y
    ssd_scan_off_kernel<<<dim3(2, NHEADS, BATCH), 256, 0, stream>>>(
        u, x_dbl, dtb, dacs, ctot, y);
    // 7. gate + RMS norm (in place on y)
    gate_norm_kernel<<<BL, 256, 0, stream>>>(y, z, norm_w);
    // 8. out = y @ W_out
    mfma_gemm<float><<<dim3(8, 128), 256, 0, stream>>>(
        y, W_outT, out, BL, DMODEL, DINNER, DINNER, DINNER, DMODEL);
}

// Round 8
// 1146.227 us; speedup vs baseline: 4.4757x; 1.7964x over previous
//
#include <hip/hip_runtime.h>
#include <hip/hip_bf16.h>

// ---- problem constants ----
#define BATCH   4
#define SEQL    4096
#define DMODEL  1024
#define DINNER  2048
#define NHEADS  32
#define HEADD   64
#define DSTATE  128
#define NCHUNK  64
#define CHUNK   64
#define BL      (BATCH * SEQL)          // 16384 rows
#define XDBLW   (NHEADS + 2 * DSTATE)   // 288
#define GC      32                      // chunks per group
#define NGROUP  2

typedef __hip_bfloat16 bf16;
typedef __attribute__((ext_vector_type(8))) short s16x8;
typedef __attribute__((ext_vector_type(8))) unsigned short u16x8;
typedef __attribute__((ext_vector_type(4))) float f32x4;

__device__ __forceinline__ float silu_f(float x) {
    return x / (1.f + expf(-x));
}
__device__ __forceinline__ float toF(float x) { return x; }
__device__ __forceinline__ float toF(bf16 x)  { return __bfloat162float(x); }
__device__ __forceinline__ void stF(float* p, float v) { *p = v; }
__device__ __forceinline__ void stF(bf16* p, float v)  { *p = __float2bfloat16(v); }
__device__ __forceinline__ float bfbits2f(unsigned short b) {
    unsigned int u = ((unsigned int)b) << 16;
    return __builtin_bit_cast(float, u);
}

// ------------------------------------------------------------------
// f32 -> bf16 bulk convert (4 per thread)
// ------------------------------------------------------------------
__global__ __launch_bounds__(256) void f32_to_bf16_kernel(
    const float* __restrict__ in, bf16* __restrict__ out, size_t n)
{
    const size_t i = ((size_t)blockIdx.x * 256 + threadIdx.x) * 4;
    if (i >= n) return;
    const float4 v = *(const float4*)(in + i);
    bf16 o[4];
    o[0] = __float2bfloat16(v.x); o[1] = __float2bfloat16(v.y);
    o[2] = __float2bfloat16(v.z); o[3] = __float2bfloat16(v.w);
    __builtin_memcpy(&out[i], o, 8);
}

// ------------------------------------------------------------------
// Transpose f32 [R][C] -> bf16 [Cpad][R], zero-pad rows c >= C.
// ------------------------------------------------------------------
__global__ __launch_bounds__(256) void transpose_to_bf16_kernel(
    const float* __restrict__ in, bf16* __restrict__ out,
    int R, int C, int Cpad)
{
    __shared__ float t[32][33];
    const int c0 = blockIdx.x * 32, r0 = blockIdx.y * 32;
    const int tx = threadIdx.x & 31, ty = threadIdx.x >> 5;  // ty 0..7
    #pragma unroll
    for (int i = 0; i < 4; i++) {
        const int r = r0 + ty + i * 8, c = c0 + tx;
        t[ty + i * 8][tx] = (c < C) ? in[(size_t)r * C + c] : 0.f;
    }
    __syncthreads();
    #pragma unroll
    for (int i = 0; i < 4; i++) {
        const int c = c0 + ty + i * 8, r = r0 + tx;
        out[(size_t)c * R + r] = __float2bfloat16(t[tx][ty + i * 8]);
    }
}

// ------------------------------------------------------------------
// MFMA bf16 GEMM: C[M,N] = A[M,K] x Bt[N,K]^T.  128x128 tile, BK=32.
// ------------------------------------------------------------------
template <typename TC>
__global__ __launch_bounds__(256) void mfma_gemm(
    const bf16* __restrict__ A, const bf16* __restrict__ Bt,
    TC* __restrict__ C, int M, int Nout, int K, int lda, int ldb, int ldc)
{
    __shared__ __align__(16) bf16 As[4096];   // [4][128][8]
    __shared__ __align__(16) bf16 Bs[4096];
    const int tid = threadIdx.x;
    const int m0 = blockIdx.y * 128;
    const int n0 = blockIdx.x * 128;
    const int wave = tid >> 6, lane = tid & 63;
    const int wr = wave >> 1, wc = wave & 1;
    const int fr = lane & 15;
    const int fq = lane >> 4;

    f32x4 acc[4][4];
    #pragma unroll
    for (int i = 0; i < 4; i++)
        #pragma unroll
        for (int j = 0; j < 4; j++)
            acc[i][j] = (f32x4){0.f, 0.f, 0.f, 0.f};

    const int srow = tid & 127;
    const int sk0 = (tid >> 7) * 8;
    const bf16* Ag = A + (size_t)(m0 + srow) * lda + sk0;
    const bf16* Bg = Bt + (size_t)(n0 + srow) * ldb + sk0;
    const int lb = (wave >> 1) * 1024 + (wave & 1) * 512;

    for (int k0 = 0; k0 < K; k0 += 32) {
        __syncthreads();
        #pragma unroll
        for (int i = 0; i < 2; i++) {
            __builtin_amdgcn_global_load_lds(
                (const __attribute__((address_space(1))) unsigned int*)(Ag + k0 + i * 16),
                (__attribute__((address_space(3))) unsigned int*)(As + i * 2048 + lb),
                16, 0, 0);
            __builtin_amdgcn_global_load_lds(
                (const __attribute__((address_space(1))) unsigned int*)(Bg + k0 + i * 16),
                (__attribute__((address_space(3))) unsigned int*)(Bs + i * 2048 + lb),
                16, 0, 0);
        }
        __syncthreads();

        s16x8 af[4], bfv[4];
        #pragma unroll
        for (int mi = 0; mi < 4; mi++)
            af[mi] = *(const s16x8*)&As[fq * 1024 + (wr * 64 + mi * 16 + fr) * 8];
        #pragma unroll
        for (int ni = 0; ni < 4; ni++)
            bfv[ni] = *(const s16x8*)&Bs[fq * 1024 + (wc * 64 + ni * 16 + fr) * 8];
        #pragma unroll
        for (int mi = 0; mi < 4; mi++)
            #pragma unroll
            for (int ni = 0; ni < 4; ni++)
                acc[mi][ni] = __builtin_amdgcn_mfma_f32_16x16x32_bf16(
                    af[mi], bfv[ni], acc[mi][ni], 0, 0, 0);
    }

    #pragma unroll
    for (int mi = 0; mi < 4; mi++) {
        #pragma unroll
        for (int ni = 0; ni < 4; ni++) {
            const int col = n0 + wc * 64 + ni * 16 + fr;
            if (col < Nout) {
                #pragma unroll
                for (int r = 0; r < 4; r++) {
                    const int row = m0 + wr * 64 + mi * 16 + fq * 4 + r;
                    stF(&C[(size_t)row * ldc + col], acc[mi][ni][r]);
                }
            }
        }
    }
}

// ------------------------------------------------------------------
// Depthwise conv (window 4, SAME pad (1,2)) + SiLU, vectorized x8.
// ------------------------------------------------------------------
__global__ __launch_bounds__(256) void conv_one_kernel(
    const bf16* __restrict__ in,
    const float* __restrict__ kern, const float* __restrict__ bias,
    bf16* __restrict__ out)
{
    const size_t gid = (size_t)blockIdx.x * 256 + threadIdx.x;
    const int d0 = ((int)(gid & 255)) << 3;
    const size_t row = gid >> 8;
    const int l = (int)(row & (SEQL - 1));
    const size_t bL = row - l;
    float a[8];
    #pragma unroll
    for (int j = 0; j < 8; j++) a[j] = bias[d0 + j];
    #pragma unroll
    for (int w = 0; w < 4; w++) {
        const int ls = l + w - 1;
        if (ls >= 0 && ls < SEQL) {
            u16x8 v;
            __builtin_memcpy(&v, &in[(bL + ls) * DINNER + d0], 16);
            #pragma unroll
            for (int j = 0; j < 8; j++)
                a[j] = fmaf(bfbits2f(v[j]), kern[w * DINNER + d0 + j], a[j]);
        }
    }
    bf16 ov[8];
    #pragma unroll
    for (int j = 0; j < 8; j++) ov[j] = __float2bfloat16(silu_f(a[j]));
    __builtin_memcpy(&out[row * DINNER + d0], ov, 16);
}

// ------------------------------------------------------------------
// dt softplus + per-chunk cumsum of dA (64-lane wave scan)
// ------------------------------------------------------------------
__global__ __launch_bounds__(256) void dt_kernel(
    const float* __restrict__ x_dbl,
    const float* __restrict__ dt_bias, const float* __restrict__ A_log,
    float* __restrict__ dtb, float* __restrict__ dacs, float* __restrict__ ctot)
{
    const int bid = blockIdx.x;
    const int hg = bid & 7;
    const int bc = bid >> 3;
    const int c = bc & (NCHUNK - 1);
    const int b = bc >> 6;
    const int w = threadIdx.x >> 6, lane = threadIdx.x & 63;
    const int h = hg * 4 + w;
    const size_t row = (size_t)b * SEQL + c * CHUNK + lane;

    const float raw = x_dbl[row * XDBLW + h] + dt_bias[h];
    const float dt = (raw > 20.f) ? raw : log1pf(expf(raw));
    dtb[row * NHEADS + h] = dt;

    float s = -expf(A_log[h]) * dt;
    #pragma unroll
    for (int off = 1; off < 64; off <<= 1) {
        const float t = __shfl_up(s, off);
        if (lane >= off) s += t;
    }
    dacs[row * NHEADS + h] = s;
    if (lane == 63) ctot[((size_t)b * NHEADS + h) * NCHUNK + c] = s;
}

// ------------------------------------------------------------------
// Chunk states (parallel over b,cg,h): S[p][n] = sum_l x[l][p]*B[l][n]*eD[l]
// eD[l] = exp(cs_last - cs[l]) * dt[l].  Output bf16 -> stG.
// ------------------------------------------------------------------
__global__ __launch_bounds__(256) void ssd_states_kernel(
    const bf16* __restrict__ u, const float* __restrict__ x_dbl,
    const float* __restrict__ dtb, const float* __restrict__ dacs,
    bf16* __restrict__ stG, int g)
{
    __shared__ float Bd[64][132];
    __shared__ float xs[64][68];
    __shared__ float csL[64], dtL[64], eD[64];
    const int h = blockIdx.x, cg = blockIdx.y, b = blockIdx.z;
    const int c = g * GC + cg;
    const int tid = threadIdx.x;
    const size_t row0 = (size_t)b * SEQL + c * CHUNK;

    if (tid < 64) {
        csL[tid] = dacs[(row0 + tid) * NHEADS + h];
        dtL[tid] = dtb[(row0 + tid) * NHEADS + h];
    }
    __syncthreads();
    if (tid < 64) eD[tid] = expf(csL[63] - csL[tid]) * dtL[tid];
    __syncthreads();

    #pragma unroll
    for (int j = 0; j < 8; j++) {
        const int f = j * 256 + tid;
        const int l = f >> 5, n0 = (f & 31) * 4;
        const float4 v = *(const float4*)&x_dbl[(row0 + l) * XDBLW + NHEADS + n0];
        const float e = eD[l];
        Bd[l][n0]     = v.x * e; Bd[l][n0 + 1] = v.y * e;
        Bd[l][n0 + 2] = v.z * e; Bd[l][n0 + 3] = v.w * e;
    }
    #pragma unroll
    for (int j = 0; j < 2; j++) {
        const int f = j * 256 + tid;
        const int l = f >> 3, p0 = (f & 7) * 8;
        u16x8 v;
        __builtin_memcpy(&v, &u[(row0 + l) * DINNER + h * HEADD + p0], 16);
        #pragma unroll
        for (int i = 0; i < 8; i++) xs[l][p0 + i] = bfbits2f(v[i]);
    }
    __syncthreads();

    const int pq = tid >> 5, ng = tid & 31;
    float acc[8][4] = {};
    #pragma unroll 8
    for (int l = 0; l < 64; l++) {
        const float4 bv = *(const float4*)&Bd[l][ng * 4];
        const float4 x0 = *(const float4*)&xs[l][pq * 8];
        const float4 x1 = *(const float4*)&xs[l][pq * 8 + 4];
        const float xv[8] = {x0.x, x0.y, x0.z, x0.w, x1.x, x1.y, x1.z, x1.w};
        const float bb[4] = {bv.x, bv.y, bv.z, bv.w};
        #pragma unroll
        for (int pp = 0; pp < 8; pp++)
            #pragma unroll
            for (int nn = 0; nn < 4; nn++)
                acc[pp][nn] = fmaf(xv[pp], bb[nn], acc[pp][nn]);
    }

    const size_t base = (((size_t)b * NHEADS + h) * GC + cg) * 8192;
    #pragma unroll
    for (int pp = 0; pp < 8; pp++) {
        bf16 ov[4];
        #pragma unroll
        for (int nn = 0; nn < 4; nn++) ov[nn] = __float2bfloat16(acc[pp][nn]);
        __builtin_memcpy(&stG[base + (pq * 8 + pp) * 128 + ng * 4], ov, 8);
    }
}

// ------------------------------------------------------------------
// Inter-chunk scan over the group (serial in c, elementwise in p,n).
// In-place: stG[c] <- run(before c); run = run*exp(ctot[c]) + s_c.
// Cross-group running state in f32 runbuf.
// ------------------------------------------------------------------
__global__ __launch_bounds__(256) void ssd_scan_kernel(
    bf16* __restrict__ stG, const float* __restrict__ ctot,
    float* __restrict__ runbuf, int g)
{
    const int q = blockIdx.x & 3, bh = blockIdx.x >> 2;  // bh = b*32+h
    const int b = bh >> 5, h = bh & 31;
    const int off = q * 2048 + threadIdx.x * 8;
    float run[8];
    if (g == 0) {
        #pragma unroll
        for (int i = 0; i < 8; i++) run[i] = 0.f;
    } else {
        const float4 r0 = *(const float4*)&runbuf[(size_t)bh * 8192 + off];
        const float4 r1 = *(const float4*)&runbuf[(size_t)bh * 8192 + off + 4];
        run[0]=r0.x; run[1]=r0.y; run[2]=r0.z; run[3]=r0.w;
        run[4]=r1.x; run[5]=r1.y; run[6]=r1.z; run[7]=r1.w;
    }
    const float* ct = ctot + ((size_t)b * NHEADS + h) * NCHUNK + g * GC;
    const size_t base = (size_t)bh * GC * 8192 + off;
    for (int c = 0; c < GC; c++) {
        u16x8 sv;
        __builtin_memcpy(&sv, &stG[base + (size_t)c * 8192], 16);
        bf16 pv[8];
        #pragma unroll
        for (int i = 0; i < 8; i++) pv[i] = __float2bfloat16(run[i]);
        __builtin_memcpy(&stG[base + (size_t)c * 8192], pv, 16);
        const float dc = expf(ct[c]);
        #pragma unroll
        for (int i = 0; i < 8; i++)
            run[i] = fmaf(run[i], dc, bfbits2f(sv[i]));
    }
    *(float4*)&runbuf[(size_t)bh * 8192 + off]     = make_float4(run[0], run[1], run[2], run[3]);
    *(float4*)&runbuf[(size_t)bh * 8192 + off + 4] = make_float4(run[4], run[5], run[6], run[7]);
}

// ------------------------------------------------------------------
// Fused Y_diag + Y_off per (b,c,h), MFMA.  Writes y IN PLACE over u.
// scores = C·B^T (MFMA) -> mask/decay/dt -> M (LDS bf16)
// Y = M·xT^T (MFMA) + eC[l] * C·prev^T (MFMA) + D*u
// LDS pitches: 152 (Cs/Bp: 16B-aligned, 2-way), 88 (xT/Ms).
// ------------------------------------------------------------------
__global__ __launch_bounds__(256) void ssd_fused_kernel(
    const bf16* __restrict__ u, const float* __restrict__ x_dbl,
    const float* __restrict__ dtb, const float* __restrict__ dacs,
    const float* __restrict__ Dv, const bf16* __restrict__ stG,
    bf16* __restrict__ y, int g)
{
    __shared__ __align__(16) bf16 Cs[64 * 152];
    __shared__ __align__(16) bf16 Bp[64 * 152];   // B (scores), then prev
    __shared__ __align__(16) bf16 xT[64 * 88];    // u tile transposed [p][l]
    __shared__ __align__(16) bf16 Ms[64 * 88];    // masked scores [l][s]
    __shared__ float csA[64], dtl[64], eC[64];

    const int h = blockIdx.x, cg = blockIdx.y, b = blockIdx.z;
    const int c = g * GC + cg;
    const int tid = threadIdx.x;
    const int wl = tid >> 6, lane = tid & 63;
    const int fr = lane & 15, fq = lane >> 4;
    const size_t row0 = (size_t)b * SEQL + c * CHUNK;

    if (tid < 64) {
        csA[tid] = dacs[(row0 + tid) * NHEADS + h];
        dtl[tid] = dtb[(row0 + tid) * NHEADS + h];
    }
    // stage C and B (f32 -> bf16), k-contiguous rows
    #pragma unroll
    for (int j = 0; j < 8; j++) {
        const int f = j * 256 + tid;
        const int l = f >> 5, n0 = (f & 31) * 4;
        const float4 cv = *(const float4*)&x_dbl[(row0 + l) * XDBLW + NHEADS + DSTATE + n0];
        const float4 bv = *(const float4*)&x_dbl[(row0 + l) * XDBLW + NHEADS + n0];
        bf16 ct[4] = {__float2bfloat16(cv.x), __float2bfloat16(cv.y),
                      __float2bfloat16(cv.z), __float2bfloat16(cv.w)};
        bf16 bt[4] = {__float2bfloat16(bv.x), __float2bfloat16(bv.y),
                      __float2bfloat16(bv.z), __float2bfloat16(bv.w)};
        __builtin_memcpy(&Cs[l * 152 + n0], ct, 8);
        __builtin_memcpy(&Bp[l * 152 + n0], bt, 8);
    }
    // stage u tile transposed: xT[p][l]
    #pragma unroll
    for (int j = 0; j < 2; j++) {
        const int f = j * 256 + tid;
        const int l = f >> 3, p0 = (f & 7) * 8;
        u16x8 v;
        __builtin_memcpy(&v, &u[(row0 + l) * DINNER + h * HEADD + p0], 16);
        #pragma unroll
        for (int i = 0; i < 8; i++)
            xT[(p0 + i) * 88 + l] = __builtin_bit_cast(bf16, (unsigned short)v[i]);
    }
    __syncthreads();
    if (tid < 64) eC[tid] = expf(csA[tid]);

    // scores = C·B^T : D[l][s], per wave l-range [wl*16, wl*16+16)
    f32x4 sf[4];
    #pragma unroll
    for (int ni = 0; ni < 4; ni++) sf[ni] = (f32x4){0.f, 0.f, 0.f, 0.f};
    #pragma unroll
    for (int kk = 0; kk < 4; kk++) {
        const s16x8 af = *(const s16x8*)&Cs[(wl * 16 + fr) * 152 + kk * 32 + fq * 8];
        #pragma unroll
        for (int ni = 0; ni < 4; ni++) {
            const s16x8 bv = *(const s16x8*)&Bp[(ni * 16 + fr) * 152 + kk * 32 + fq * 8];
            sf[ni] = __builtin_amdgcn_mfma_f32_16x16x32_bf16(af, bv, sf[ni], 0, 0, 0);
        }
    }
    // mask/decay/dt -> Ms[l][s]
    #pragma unroll
    for (int ni = 0; ni < 4; ni++) {
        const int s = ni * 16 + fr;
        #pragma unroll
        for (int r = 0; r < 4; r++) {
            const int l = wl * 16 + fq * 4 + r;
            float v = 0.f;
            if (l >= s) v = sf[ni][r] * expf(csA[l] - csA[s]) * dtl[s];
            Ms[l * 88 + s] = __float2bfloat16(v);
        }
    }
    __syncthreads();   // Ms/eC ready; Bp (scores reads) done -> restage prev
    // stage prev into Bp: [p][n] rows k(n)-contiguous
    const size_t sbase = (((size_t)b * NHEADS + h) * GC + cg) * 8192;
    #pragma unroll
    for (int j = 0; j < 4; j++) {
        const int f = j * 256 + tid;
        const int p = f >> 4, n0 = (f & 15) * 8;
        u16x8 v;
        __builtin_memcpy(&v, &stG[sbase + p * 128 + n0], 16);
        __builtin_memcpy(&Bp[p * 152 + n0], &v, 16);
    }
    __syncthreads();

    // Y_diag = M·xT^T  (K=64) and Y_off = C·prev^T (K=128)
    f32x4 ady[4], aof[4];
    #pragma unroll
    for (int ni = 0; ni < 4; ni++) {
        ady[ni] = (f32x4){0.f, 0.f, 0.f, 0.f};
        aof[ni] = (f32x4){0.f, 0.f, 0.f, 0.f};
    }
    #pragma unroll
    for (int kk = 0; kk < 2; kk++) {
        const s16x8 af = *(const s16x8*)&Ms[(wl * 16 + fr) * 88 + kk * 32 + fq * 8];
        #pragma unroll
        for (int ni = 0; ni < 4; ni++) {
            const s16x8 bv = *(const s16x8*)&xT[(ni * 16 + fr) * 88 + kk * 32 + fq * 8];
            ady[ni] = __builtin_amdgcn_mfma_f32_16x16x32_bf16(af, bv, ady[ni], 0, 0, 0);
        }
    }
    #pragma unroll
    for (int kk = 0; kk < 4; kk++) {
        const s16x8 af = *(const s16x8*)&Cs[(wl * 16 + fr) * 152 + kk * 32 + fq * 8];
        #pragma unroll
        for (int ni = 0; ni < 4; ni++) {
            const s16x8 bv = *(const s16x8*)&Bp[(ni * 16 + fr) * 152 + kk * 32 + fq * 8];
            aof[ni] = __builtin_amdgcn_mfma_f32_16x16x32_bf16(af, bv, aof[ni], 0, 0, 0);
        }
    }
    // epilogue: y = ady + eC[l]*aof + D*u   (in place over u; disjoint tiles)
    const float Dh = Dv[h];
    #pragma unroll
    for (int ni = 0; ni < 4; ni++) {
        const int p = ni * 16 + fr;
        #pragma unroll
        for (int r = 0; r < 4; r++) {
            const int l = wl * 16 + fq * 4 + r;
            const float uval = toF(xT[p * 88 + l]);
            const float val = ady[ni][r] + eC[l] * aof[ni][r] + Dh * uval;
            y[(row0 + l) * DINNER + h * HEADD + p] = __float2bfloat16(val);
        }
    }
}

// ------------------------------------------------------------------
// y = y * silu(z); RMS-norm over DINNER; * norm_w.  In place on y.
// ------------------------------------------------------------------
__global__ __launch_bounds__(256) void gate_norm_kernel(
    bf16* __restrict__ y, const bf16* __restrict__ z,
    const float* __restrict__ norm_w)
{
    __shared__ float red[4];
    const size_t row = blockIdx.x;
    const int tid = threadIdx.x;
    const int d0 = tid * 8;
    u16x8 yv, zv;
    __builtin_memcpy(&yv, &y[row * DINNER + d0], 16);
    __builtin_memcpy(&zv, &z[row * DINNER + d0], 16);
    float v[8];
    float ss = 0.f;
    #pragma unroll
    for (int j = 0; j < 8; j++) {
        const float val = bfbits2f(yv[j]) * silu_f(bfbits2f(zv[j]));
        v[j] = val;
        ss = fmaf(val, val, ss);
    }
    #pragma unroll
    for (int off = 32; off > 0; off >>= 1) ss += __shfl_down(ss, off);
    const int lane = tid & 63, w = tid >> 6;
    if (lane == 0) red[w] = ss;
    __syncthreads();
    const float tot = red[0] + red[1] + red[2] + red[3];
    const float scale = rsqrtf(tot / (float)DINNER + 1e-6f);
    bf16 ov[8];
    #pragma unroll
    for (int j = 0; j < 8; j++)
        ov[j] = __float2bfloat16(v[j] * scale * norm_w[d0 + j]);
    __builtin_memcpy(&y[row * DINNER + d0], ov, 16);
}

// ------------------------------------------------------------------
extern "C" void kernel_launch(void* const* d_in, const int* in_sizes, int n_in,
                              void* d_out, int out_size, void* d_ws, size_t ws_size,
                              hipStream_t stream)
{
    const float* x       = (const float*)d_in[0];
    const float* W_in    = (const float*)d_in[1];
    const float* conv_xk = (const float*)d_in[2];
    const float* conv_xb = (const float*)d_in[3];
    const float* conv_zk = (const float*)d_in[4];
    const float* conv_zb = (const float*)d_in[5];
    const float* W_x     = (const float*)d_in[6];
    const float* dt_bias = (const float*)d_in[7];
    const float* A_log   = (const float*)d_in[8];
    const float* Dv      = (const float*)d_in[9];
    const float* norm_w  = (const float*)d_in[10];
    const float* W_out   = (const float*)d_in[11];
    float* out = (float*)d_out;
    char* ws   = (char*)d_ws;

    // workspace layout (bytes), peak 234,389,504 (~224 MB):
    //  xbf:    [0,            33,554,432)   bf16 x (dead after GEMM 2a)
    //  W_inT:  [33,554,432,   41,943,040)   bf16 (dead after 2a)
    //  u:      [0,            67,108,864)   bf16 (y written in place by fused)
    //  z:      [67,108,864,   134,217,728)  bf16
    //  scr:    [134,217,728,  201,326,592)  bf16: zpre -> upre -> stG (group states)
    //  x_dbl:  [201,326,592,  220,200,960)  f32
    //  dtb:    [220,200,960,  222,298,112)  f32
    //  dacs:   [222,298,112,  224,395,264)  f32
    //  ctot:   [224,395,264,  224,428,032)  f32
    //  W_xT:   [224,428,032,  226,000,896)  bf16 [384][2048] zero-padded
    //  W_outT: [226,000,896,  230,195,200)  bf16 [1024][2048]
    //  runbuf: [230,195,200,  234,389,504)  f32 [128][8192]
    if (ws_size < (size_t)234389504) return;   // diagnostic guard
    bf16*  xbf    = (bf16*)(ws);
    bf16*  W_inT  = (bf16*)(ws + 33554432);
    bf16*  u      = (bf16*)(ws);
    bf16*  z      = (bf16*)(ws + 67108864);
    bf16*  scr    = (bf16*)(ws + 134217728);   // zpre / upre / stG
    float* x_dbl  = (float*)(ws + 201326592);
    float* dtb    = (float*)(ws + 220200960);
    float* dacs   = (float*)(ws + 222298112);
    float* ctot   = (float*)(ws + 224395264);
    bf16*  W_xT   = (bf16*)(ws + 224428032);
    bf16*  W_outT = (bf16*)(ws + 226000896);
    float* runbuf = (float*)(ws + 230195200);
    bf16* stG = scr;
    bf16* y   = u;    // fused kernel writes y in place over u

    // 0. convert x to bf16; transpose weights to bf16 B^T layouts
    f32_to_bf16_kernel<<<16384, 256, 0, stream>>>(x, xbf, (size_t)BL * DMODEL);
    transpose_to_bf16_kernel<<<dim3(128, 32), 256, 0, stream>>>(
        W_in, W_inT, DMODEL, 2 * DINNER, 2 * DINNER);
    transpose_to_bf16_kernel<<<dim3(12, 64), 256, 0, stream>>>(
        W_x, W_xT, DINNER, XDBLW, 384);
    transpose_to_bf16_kernel<<<dim3(32, 64), 256, 0, stream>>>(
        W_out, W_outT, DINNER, DMODEL, DMODEL);

    // 1a. zpre = x @ W_in[:, 2048:4096] → scr
    mfma_gemm<bf16><<<dim3(16, 128), 256, 0, stream>>>(
        xbf, W_inT + (size_t)DINNER * DMODEL, scr, BL, DINNER, DMODEL,
        DMODEL, DMODEL, DINNER);
    // 1b. z = silu(conv(zpre))
    conv_one_kernel<<<BL, 256, 0, stream>>>(scr, conv_zk, conv_zb, z);
    // 2a. upre = x @ W_in[:, 0:2048] → scr (zpre dead)
    mfma_gemm<bf16><<<dim3(16, 128), 256, 0, stream>>>(
        xbf, W_inT, scr, BL, DINNER, DMODEL, DMODEL, DMODEL, DINNER);
    // 2b. u = silu(conv(upre))  (overwrites xbf/W_inT region — both dead)
    conv_one_kernel<<<BL, 256, 0, stream>>>(scr, conv_xk, conv_xb, u);
    // 3. x_dbl = u @ W_x
    mfma_gemm<float><<<dim3(3, 128), 256, 0, stream>>>(
        u, W_xT, x_dbl, BL, XDBLW, DINNER, DINNER, DINNER, XDBLW);
    // 4. dt / dA cumsums
    dt_kernel<<<BATCH * NCHUNK * 8, 256, 0, stream>>>(
        x_dbl, dt_bias, A_log, dtb, dacs, ctot);
    // 5. SSD per group: states (parallel) -> scan (serial-c) -> fused diag+off
    for (int g = 0; g < NGROUP; g++) {
        ssd_states_kernel<<<dim3(NHEADS, GC, BATCH), 256, 0, stream>>>(
            u, x_dbl, dtb, dacs, stG, g);
        ssd_scan_kernel<<<512, 256, 0, stream>>>(stG, ctot, runbuf, g);
        ssd_fused_kernel<<<dim3(NHEADS, GC, BATCH), 256, 0, stream>>>(
            u, x_dbl, dtb, dacs, Dv, stG, y, g);
    }
    // 6. gate + RMS norm (in place on y = u region)
    gate_norm_kernel<<<BL, 256, 0, stream>>>(y, z, norm_w);
    // 7. out = y @ W_out
    mfma_gemm<float><<<dim3(8, 128), 256, 0, stream>>>(
        y, W_outT, out, BL, DMODEL, DINNER, DINNER, DINNER, DMODEL);
}

// Round 9
// 1095.582 us; speedup vs baseline: 4.6826x; 1.0462x over previous
//
#include <hip/hip_runtime.h>
#include <hip/hip_bf16.h>

// ---- problem constants ----
#define BATCH   4
#define SEQL    4096
#define DMODEL  1024
#define DINNER  2048
#define NHEADS  32
#define HEADD   64
#define DSTATE  128
#define NCHUNK  64
#define CHUNK   64
#define BL      (BATCH * SEQL)          // 16384 rows
#define XDBLW   (NHEADS + 2 * DSTATE)   // 288
#define GC      32                      // chunks per group
#define NGROUP  2

typedef __hip_bfloat16 bf16;
typedef __attribute__((ext_vector_type(8))) short s16x8;
typedef __attribute__((ext_vector_type(8))) unsigned short u16x8;
typedef __attribute__((ext_vector_type(4))) float f32x4;

__device__ __forceinline__ float silu_f(float x) {
    return x / (1.f + expf(-x));
}
__device__ __forceinline__ float toF(float x) { return x; }
__device__ __forceinline__ float toF(bf16 x)  { return __bfloat162float(x); }
__device__ __forceinline__ void stF(float* p, float v) { *p = v; }
__device__ __forceinline__ void stF(bf16* p, float v)  { *p = __float2bfloat16(v); }
__device__ __forceinline__ float bfbits2f(unsigned short b) {
    unsigned int u = ((unsigned int)b) << 16;
    return __builtin_bit_cast(float, u);
}

// ------------------------------------------------------------------
// f32 -> bf16 bulk convert (4 per thread)
// ------------------------------------------------------------------
__global__ __launch_bounds__(256) void f32_to_bf16_kernel(
    const float* __restrict__ in, bf16* __restrict__ out, size_t n)
{
    const size_t i = ((size_t)blockIdx.x * 256 + threadIdx.x) * 4;
    if (i >= n) return;
    const float4 v = *(const float4*)(in + i);
    bf16 o[4];
    o[0] = __float2bfloat16(v.x); o[1] = __float2bfloat16(v.y);
    o[2] = __float2bfloat16(v.z); o[3] = __float2bfloat16(v.w);
    __builtin_memcpy(&out[i], o, 8);
}

// ------------------------------------------------------------------
// Transpose f32 [R][C] -> bf16 [Cpad][R], zero-pad rows c >= C.
// ------------------------------------------------------------------
__global__ __launch_bounds__(256) void transpose_to_bf16_kernel(
    const float* __restrict__ in, bf16* __restrict__ out,
    int R, int C, int Cpad)
{
    __shared__ float t[32][33];
    const int c0 = blockIdx.x * 32, r0 = blockIdx.y * 32;
    const int tx = threadIdx.x & 31, ty = threadIdx.x >> 5;  // ty 0..7
    #pragma unroll
    for (int i = 0; i < 4; i++) {
        const int r = r0 + ty + i * 8, c = c0 + tx;
        t[ty + i * 8][tx] = (c < C) ? in[(size_t)r * C + c] : 0.f;
    }
    __syncthreads();
    #pragma unroll
    for (int i = 0; i < 4; i++) {
        const int c = c0 + ty + i * 8, r = r0 + tx;
        out[(size_t)c * R + r] = __float2bfloat16(t[tx][ty + i * 8]);
    }
}

// ------------------------------------------------------------------
// MFMA bf16 GEMM: C[M,N] = A[M,K] x Bt[N,K]^T.  128x128 tile, BK=32.
// XCD-aware bijective block swizzle (m204) for per-XCD L2 reuse.
// ------------------------------------------------------------------
template <typename TC>
__global__ __launch_bounds__(256) void mfma_gemm(
    const bf16* __restrict__ A, const bf16* __restrict__ Bt,
    TC* __restrict__ C, int M, int Nout, int K, int lda, int ldb, int ldc)
{
    __shared__ __align__(16) bf16 As[4096];   // [4][128][8]
    __shared__ __align__(16) bf16 Bs[4096];
    const int tid = threadIdx.x;

    // XCD swizzle: consecutive swz tiles land on the same XCD
    const int nwg = gridDim.x * gridDim.y;
    const int orig = blockIdx.y * gridDim.x + blockIdx.x;
    const int q = nwg >> 3, r = nwg & 7;
    const int xcd = orig & 7, loc = orig >> 3;
    const int swz = (xcd < r ? xcd * (q + 1) : r * (q + 1) + (xcd - r) * q) + loc;
    const int m0 = (swz / gridDim.x) * 128;
    const int n0 = (swz % gridDim.x) * 128;

    const int wave = tid >> 6, lane = tid & 63;
    const int wr = wave >> 1, wc = wave & 1;
    const int fr = lane & 15;
    const int fq = lane >> 4;

    f32x4 acc[4][4];
    #pragma unroll
    for (int i = 0; i < 4; i++)
        #pragma unroll
        for (int j = 0; j < 4; j++)
            acc[i][j] = (f32x4){0.f, 0.f, 0.f, 0.f};

    const int srow = tid & 127;
    const int sk0 = (tid >> 7) * 8;
    const bf16* Ag = A + (size_t)(m0 + srow) * lda + sk0;
    const bf16* Bg = Bt + (size_t)(n0 + srow) * ldb + sk0;
    const int lb = (wave >> 1) * 1024 + (wave & 1) * 512;

    for (int k0 = 0; k0 < K; k0 += 32) {
        __syncthreads();
        #pragma unroll
        for (int i = 0; i < 2; i++) {
            __builtin_amdgcn_global_load_lds(
                (const __attribute__((address_space(1))) unsigned int*)(Ag + k0 + i * 16),
                (__attribute__((address_space(3))) unsigned int*)(As + i * 2048 + lb),
                16, 0, 0);
            __builtin_amdgcn_global_load_lds(
                (const __attribute__((address_space(1))) unsigned int*)(Bg + k0 + i * 16),
                (__attribute__((address_space(3))) unsigned int*)(Bs + i * 2048 + lb),
                16, 0, 0);
        }
        __syncthreads();

        s16x8 af[4], bfv[4];
        #pragma unroll
        for (int mi = 0; mi < 4; mi++)
            af[mi] = *(const s16x8*)&As[fq * 1024 + (wr * 64 + mi * 16 + fr) * 8];
        #pragma unroll
        for (int ni = 0; ni < 4; ni++)
            bfv[ni] = *(const s16x8*)&Bs[fq * 1024 + (wc * 64 + ni * 16 + fr) * 8];
        #pragma unroll
        for (int mi = 0; mi < 4; mi++)
            #pragma unroll
            for (int ni = 0; ni < 4; ni++)
                acc[mi][ni] = __builtin_amdgcn_mfma_f32_16x16x32_bf16(
                    af[mi], bfv[ni], acc[mi][ni], 0, 0, 0);
    }

    #pragma unroll
    for (int mi = 0; mi < 4; mi++) {
        #pragma unroll
        for (int ni = 0; ni < 4; ni++) {
            const int col = n0 + wc * 64 + ni * 16 + fr;
            if (col < Nout) {
                #pragma unroll
                for (int r2 = 0; r2 < 4; r2++) {
                    const int row = m0 + wr * 64 + mi * 16 + fq * 4 + r2;
                    stF(&C[(size_t)row * ldc + col], acc[mi][ni][r2]);
                }
            }
        }
    }
}

// ------------------------------------------------------------------
// Depthwise conv (window 4, SAME pad (1,2)) + SiLU, vectorized x8.
// ------------------------------------------------------------------
__global__ __launch_bounds__(256) void conv_one_kernel(
    const bf16* __restrict__ in,
    const float* __restrict__ kern, const float* __restrict__ bias,
    bf16* __restrict__ out)
{
    const size_t gid = (size_t)blockIdx.x * 256 + threadIdx.x;
    const int d0 = ((int)(gid & 255)) << 3;
    const size_t row = gid >> 8;
    const int l = (int)(row & (SEQL - 1));
    const size_t bL = row - l;
    float a[8];
    #pragma unroll
    for (int j = 0; j < 8; j++) a[j] = bias[d0 + j];
    #pragma unroll
    for (int w = 0; w < 4; w++) {
        const int ls = l + w - 1;
        if (ls >= 0 && ls < SEQL) {
            u16x8 v;
            __builtin_memcpy(&v, &in[(bL + ls) * DINNER + d0], 16);
            #pragma unroll
            for (int j = 0; j < 8; j++)
                a[j] = fmaf(bfbits2f(v[j]), kern[w * DINNER + d0 + j], a[j]);
        }
    }
    bf16 ov[8];
    #pragma unroll
    for (int j = 0; j < 8; j++) ov[j] = __float2bfloat16(silu_f(a[j]));
    __builtin_memcpy(&out[row * DINNER + d0], ov, 16);
}

// ------------------------------------------------------------------
// dt softplus + per-chunk cumsum of dA (64-lane wave scan)
// ------------------------------------------------------------------
__global__ __launch_bounds__(256) void dt_kernel(
    const float* __restrict__ x_dbl,
    const float* __restrict__ dt_bias, const float* __restrict__ A_log,
    float* __restrict__ dtb, float* __restrict__ dacs, float* __restrict__ ctot)
{
    const int bid = blockIdx.x;
    const int hg = bid & 7;
    const int bc = bid >> 3;
    const int c = bc & (NCHUNK - 1);
    const int b = bc >> 6;
    const int w = threadIdx.x >> 6, lane = threadIdx.x & 63;
    const int h = hg * 4 + w;
    const size_t row = (size_t)b * SEQL + c * CHUNK + lane;

    const float raw = x_dbl[row * XDBLW + h] + dt_bias[h];
    const float dt = (raw > 20.f) ? raw : log1pf(expf(raw));
    dtb[row * NHEADS + h] = dt;

    float s = -expf(A_log[h]) * dt;
    #pragma unroll
    for (int off = 1; off < 64; off <<= 1) {
        const float t = __shfl_up(s, off);
        if (lane >= off) s += t;
    }
    dacs[row * NHEADS + h] = s;
    if (lane == 63) ctot[((size_t)b * NHEADS + h) * NCHUNK + c] = s;
}

// ------------------------------------------------------------------
// Chunk states via MFMA: S[p][n] = sum_l x[l][p] * (B[l][n]*eD[l])
// A = xT[p][l], B = Bdt[n][l] (both l-contiguous, pitch 72 elem).
// Wave wv covers n in [wv*32, wv*32+32); all 4 p-frags; K=64.
// ------------------------------------------------------------------
__global__ __launch_bounds__(256) void ssd_states_kernel(
    const bf16* __restrict__ u, const float* __restrict__ x_dbl,
    const float* __restrict__ dtb, const float* __restrict__ dacs,
    bf16* __restrict__ stG, int g)
{
    __shared__ __align__(16) bf16 Bdt[128 * 72];
    __shared__ __align__(16) bf16 xT[64 * 72];
    __shared__ float csL[64], dtL[64], eD[64];
    const int h = blockIdx.x, cg = blockIdx.y, b = blockIdx.z;
    const int c = g * GC + cg;
    const int tid = threadIdx.x;
    const int wv = tid >> 6, lane = tid & 63;
    const int fr = lane & 15, fq = lane >> 4;
    const size_t row0 = (size_t)b * SEQL + c * CHUNK;

    if (tid < 64) {
        csL[tid] = dacs[(row0 + tid) * NHEADS + h];
        dtL[tid] = dtb[(row0 + tid) * NHEADS + h];
    }
    __syncthreads();
    if (tid < 64) eD[tid] = expf(csL[63] - csL[tid]) * dtL[tid];
    __syncthreads();

    // Bdt[n][l] = B[l][n] * eD[l]  (transpose during staging)
    #pragma unroll
    for (int j = 0; j < 8; j++) {
        const int f = j * 256 + tid;
        const int l = f >> 5, n0 = (f & 31) * 4;
        const float4 v = *(const float4*)&x_dbl[(row0 + l) * XDBLW + NHEADS + n0];
        const float e = eD[l];
        Bdt[(n0    ) * 72 + l] = __float2bfloat16(v.x * e);
        Bdt[(n0 + 1) * 72 + l] = __float2bfloat16(v.y * e);
        Bdt[(n0 + 2) * 72 + l] = __float2bfloat16(v.z * e);
        Bdt[(n0 + 3) * 72 + l] = __float2bfloat16(v.w * e);
    }
    // xT[p][l] from u (transpose during staging)
    #pragma unroll
    for (int j = 0; j < 2; j++) {
        const int f = j * 256 + tid;
        const int l = f >> 3, p0 = (f & 7) * 8;
        u16x8 v;
        __builtin_memcpy(&v, &u[(row0 + l) * DINNER + h * HEADD + p0], 16);
        #pragma unroll
        for (int i = 0; i < 8; i++)
            xT[(p0 + i) * 72 + l] = __builtin_bit_cast(bf16, (unsigned short)v[i]);
    }
    __syncthreads();

    f32x4 acc[4][2];
    #pragma unroll
    for (int mi = 0; mi < 4; mi++)
        #pragma unroll
        for (int ni = 0; ni < 2; ni++)
            acc[mi][ni] = (f32x4){0.f, 0.f, 0.f, 0.f};
    #pragma unroll
    for (int kk = 0; kk < 2; kk++) {
        s16x8 bv0 = *(const s16x8*)&Bdt[(wv * 32 + fr) * 72 + kk * 32 + fq * 8];
        s16x8 bv1 = *(const s16x8*)&Bdt[(wv * 32 + 16 + fr) * 72 + kk * 32 + fq * 8];
        #pragma unroll
        for (int mi = 0; mi < 4; mi++) {
            const s16x8 af = *(const s16x8*)&xT[(mi * 16 + fr) * 72 + kk * 32 + fq * 8];
            acc[mi][0] = __builtin_amdgcn_mfma_f32_16x16x32_bf16(af, bv0, acc[mi][0], 0, 0, 0);
            acc[mi][1] = __builtin_amdgcn_mfma_f32_16x16x32_bf16(af, bv1, acc[mi][1], 0, 0, 0);
        }
    }

    const size_t base = (((size_t)b * NHEADS + h) * GC + cg) * 8192;
    #pragma unroll
    for (int mi = 0; mi < 4; mi++)
        #pragma unroll
        for (int ni = 0; ni < 2; ni++) {
            const int n = wv * 32 + ni * 16 + fr;
            #pragma unroll
            for (int r = 0; r < 4; r++) {
                const int p = mi * 16 + fq * 4 + r;
                stG[base + p * 128 + n] = __float2bfloat16(acc[mi][ni][r]);
            }
        }
}

// ------------------------------------------------------------------
// Inter-chunk scan over the group (serial in c, elementwise in p,n).
// ------------------------------------------------------------------
__global__ __launch_bounds__(256) void ssd_scan_kernel(
    bf16* __restrict__ stG, const float* __restrict__ ctot,
    float* __restrict__ runbuf, int g)
{
    const int q = blockIdx.x & 3, bh = blockIdx.x >> 2;  // bh = b*32+h
    const int b = bh >> 5, h = bh & 31;
    const int off = q * 2048 + threadIdx.x * 8;
    float run[8];
    if (g == 0) {
        #pragma unroll
        for (int i = 0; i < 8; i++) run[i] = 0.f;
    } else {
        const float4 r0 = *(const float4*)&runbuf[(size_t)bh * 8192 + off];
        const float4 r1 = *(const float4*)&runbuf[(size_t)bh * 8192 + off + 4];
        run[0]=r0.x; run[1]=r0.y; run[2]=r0.z; run[3]=r0.w;
        run[4]=r1.x; run[5]=r1.y; run[6]=r1.z; run[7]=r1.w;
    }
    const float* ct = ctot + ((size_t)b * NHEADS + h) * NCHUNK + g * GC;
    const size_t base = (size_t)bh * GC * 8192 + off;
    for (int c = 0; c < GC; c++) {
        u16x8 sv;
        __builtin_memcpy(&sv, &stG[base + (size_t)c * 8192], 16);
        bf16 pv[8];
        #pragma unroll
        for (int i = 0; i < 8; i++) pv[i] = __float2bfloat16(run[i]);
        __builtin_memcpy(&stG[base + (size_t)c * 8192], pv, 16);
        const float dc = expf(ct[c]);
        #pragma unroll
        for (int i = 0; i < 8; i++)
            run[i] = fmaf(run[i], dc, bfbits2f(sv[i]));
    }
    *(float4*)&runbuf[(size_t)bh * 8192 + off]     = make_float4(run[0], run[1], run[2], run[3]);
    *(float4*)&runbuf[(size_t)bh * 8192 + off + 4] = make_float4(run[4], run[5], run[6], run[7]);
}

// ------------------------------------------------------------------
// Fused Y_diag + Y_off per (b,c,h), MFMA.  Writes y IN PLACE over u.
// ------------------------------------------------------------------
__global__ __launch_bounds__(256) void ssd_fused_kernel(
    const bf16* __restrict__ u, const float* __restrict__ x_dbl,
    const float* __restrict__ dtb, const float* __restrict__ dacs,
    const float* __restrict__ Dv, const bf16* __restrict__ stG,
    bf16* __restrict__ y, int g)
{
    __shared__ __align__(16) bf16 Cs[64 * 152];
    __shared__ __align__(16) bf16 Bp[64 * 152];   // B (scores), then prev
    __shared__ __align__(16) bf16 xT[64 * 88];    // u tile transposed [p][l]
    __shared__ __align__(16) bf16 Ms[64 * 88];    // masked scores [l][s]
    __shared__ float csA[64], dtl[64], eC[64];

    const int h = blockIdx.x, cg = blockIdx.y, b = blockIdx.z;
    const int c = g * GC + cg;
    const int tid = threadIdx.x;
    const int wl = tid >> 6, lane = tid & 63;
    const int fr = lane & 15, fq = lane >> 4;
    const size_t row0 = (size_t)b * SEQL + c * CHUNK;

    if (tid < 64) {
        csA[tid] = dacs[(row0 + tid) * NHEADS + h];
        dtl[tid] = dtb[(row0 + tid) * NHEADS + h];
    }
    #pragma unroll
    for (int j = 0; j < 8; j++) {
        const int f = j * 256 + tid;
        const int l = f >> 5, n0 = (f & 31) * 4;
        const float4 cv = *(const float4*)&x_dbl[(row0 + l) * XDBLW + NHEADS + DSTATE + n0];
        const float4 bv = *(const float4*)&x_dbl[(row0 + l) * XDBLW + NHEADS + n0];
        bf16 ct[4] = {__float2bfloat16(cv.x), __float2bfloat16(cv.y),
                      __float2bfloat16(cv.z), __float2bfloat16(cv.w)};
        bf16 bt[4] = {__float2bfloat16(bv.x), __float2bfloat16(bv.y),
                      __float2bfloat16(bv.z), __float2bfloat16(bv.w)};
        __builtin_memcpy(&Cs[l * 152 + n0], ct, 8);
        __builtin_memcpy(&Bp[l * 152 + n0], bt, 8);
    }
    #pragma unroll
    for (int j = 0; j < 2; j++) {
        const int f = j * 256 + tid;
        const int l = f >> 3, p0 = (f & 7) * 8;
        u16x8 v;
        __builtin_memcpy(&v, &u[(row0 + l) * DINNER + h * HEADD + p0], 16);
        #pragma unroll
        for (int i = 0; i < 8; i++)
            xT[(p0 + i) * 88 + l] = __builtin_bit_cast(bf16, (unsigned short)v[i]);
    }
    __syncthreads();
    if (tid < 64) eC[tid] = expf(csA[tid]);

    // scores = C·B^T
    f32x4 sf[4];
    #pragma unroll
    for (int ni = 0; ni < 4; ni++) sf[ni] = (f32x4){0.f, 0.f, 0.f, 0.f};
    #pragma unroll
    for (int kk = 0; kk < 4; kk++) {
        const s16x8 af = *(const s16x8*)&Cs[(wl * 16 + fr) * 152 + kk * 32 + fq * 8];
        #pragma unroll
        for (int ni = 0; ni < 4; ni++) {
            const s16x8 bv = *(const s16x8*)&Bp[(ni * 16 + fr) * 152 + kk * 32 + fq * 8];
            sf[ni] = __builtin_amdgcn_mfma_f32_16x16x32_bf16(af, bv, sf[ni], 0, 0, 0);
        }
    }
    #pragma unroll
    for (int ni = 0; ni < 4; ni++) {
        const int s = ni * 16 + fr;
        #pragma unroll
        for (int r = 0; r < 4; r++) {
            const int l = wl * 16 + fq * 4 + r;
            float v = 0.f;
            if (l >= s) v = sf[ni][r] * expf(csA[l] - csA[s]) * dtl[s];
            Ms[l * 88 + s] = __float2bfloat16(v);
        }
    }
    __syncthreads();
    const size_t sbase = (((size_t)b * NHEADS + h) * GC + cg) * 8192;
    #pragma unroll
    for (int j = 0; j < 4; j++) {
        const int f = j * 256 + tid;
        const int p = f >> 4, n0 = (f & 15) * 8;
        u16x8 v;
        __builtin_memcpy(&v, &stG[sbase + p * 128 + n0], 16);
        __builtin_memcpy(&Bp[p * 152 + n0], &v, 16);
    }
    __syncthreads();

    f32x4 ady[4], aof[4];
    #pragma unroll
    for (int ni = 0; ni < 4; ni++) {
        ady[ni] = (f32x4){0.f, 0.f, 0.f, 0.f};
        aof[ni] = (f32x4){0.f, 0.f, 0.f, 0.f};
    }
    #pragma unroll
    for (int kk = 0; kk < 2; kk++) {
        const s16x8 af = *(const s16x8*)&Ms[(wl * 16 + fr) * 88 + kk * 32 + fq * 8];
        #pragma unroll
        for (int ni = 0; ni < 4; ni++) {
            const s16x8 bv = *(const s16x8*)&xT[(ni * 16 + fr) * 88 + kk * 32 + fq * 8];
            ady[ni] = __builtin_amdgcn_mfma_f32_16x16x32_bf16(af, bv, ady[ni], 0, 0, 0);
        }
    }
    #pragma unroll
    for (int kk = 0; kk < 4; kk++) {
        const s16x8 af = *(const s16x8*)&Cs[(wl * 16 + fr) * 152 + kk * 32 + fq * 8];
        #pragma unroll
        for (int ni = 0; ni < 4; ni++) {
            const s16x8 bv = *(const s16x8*)&Bp[(ni * 16 + fr) * 152 + kk * 32 + fq * 8];
            aof[ni] = __builtin_amdgcn_mfma_f32_16x16x32_bf16(af, bv, aof[ni], 0, 0, 0);
        }
    }
    const float Dh = Dv[h];
    #pragma unroll
    for (int ni = 0; ni < 4; ni++) {
        const int p = ni * 16 + fr;
        #pragma unroll
        for (int r = 0; r < 4; r++) {
            const int l = wl * 16 + fq * 4 + r;
            const float uval = toF(xT[p * 88 + l]);
            const float val = ady[ni][r] + eC[l] * aof[ni][r] + Dh * uval;
            y[(row0 + l) * DINNER + h * HEADD + p] = __float2bfloat16(val);
        }
    }
}

// ------------------------------------------------------------------
// y = y * silu(z); RMS-norm over DINNER; * norm_w.  In place on y.
// ------------------------------------------------------------------
__global__ __launch_bounds__(256) void gate_norm_kernel(
    bf16* __restrict__ y, const bf16* __restrict__ z,
    const float* __restrict__ norm_w)
{
    __shared__ float red[4];
    const size_t row = blockIdx.x;
    const int tid = threadIdx.x;
    const int d0 = tid * 8;
    u16x8 yv, zv;
    __builtin_memcpy(&yv, &y[row * DINNER + d0], 16);
    __builtin_memcpy(&zv, &z[row * DINNER + d0], 16);
    float v[8];
    float ss = 0.f;
    #pragma unroll
    for (int j = 0; j < 8; j++) {
        const float val = bfbits2f(yv[j]) * silu_f(bfbits2f(zv[j]));
        v[j] = val;
        ss = fmaf(val, val, ss);
    }
    #pragma unroll
    for (int off = 32; off > 0; off >>= 1) ss += __shfl_down(ss, off);
    const int lane = tid & 63, w = tid >> 6;
    if (lane == 0) red[w] = ss;
    __syncthreads();
    const float tot = red[0] + red[1] + red[2] + red[3];
    const float scale = rsqrtf(tot / (float)DINNER + 1e-6f);
    bf16 ov[8];
    #pragma unroll
    for (int j = 0; j < 8; j++)
        ov[j] = __float2bfloat16(v[j] * scale * norm_w[d0 + j]);
    __builtin_memcpy(&y[row * DINNER + d0], ov, 16);
}

// ------------------------------------------------------------------
extern "C" void kernel_launch(void* const* d_in, const int* in_sizes, int n_in,
                              void* d_out, int out_size, void* d_ws, size_t ws_size,
                              hipStream_t stream)
{
    const float* x       = (const float*)d_in[0];
    const float* W_in    = (const float*)d_in[1];
    const float* conv_xk = (const float*)d_in[2];
    const float* conv_xb = (const float*)d_in[3];
    const float* conv_zk = (const float*)d_in[4];
    const float* conv_zb = (const float*)d_in[5];
    const float* W_x     = (const float*)d_in[6];
    const float* dt_bias = (const float*)d_in[7];
    const float* A_log   = (const float*)d_in[8];
    const float* Dv      = (const float*)d_in[9];
    const float* norm_w  = (const float*)d_in[10];
    const float* W_out   = (const float*)d_in[11];
    float* out = (float*)d_out;
    char* ws   = (char*)d_ws;

    // workspace layout (bytes), peak 234,389,504 (~224 MB) — see round 7.
    if (ws_size < (size_t)234389504) return;   // diagnostic guard
    bf16*  xbf    = (bf16*)(ws);
    bf16*  W_inT  = (bf16*)(ws + 33554432);
    bf16*  u      = (bf16*)(ws);
    bf16*  z      = (bf16*)(ws + 67108864);
    bf16*  scr    = (bf16*)(ws + 134217728);   // zpre / upre / stG
    float* x_dbl  = (float*)(ws + 201326592);
    float* dtb    = (float*)(ws + 220200960);
    float* dacs   = (float*)(ws + 222298112);
    float* ctot   = (float*)(ws + 224395264);
    bf16*  W_xT   = (bf16*)(ws + 224428032);
    bf16*  W_outT = (bf16*)(ws + 226000896);
    float* runbuf = (float*)(ws + 230195200);
    bf16* stG = scr;
    bf16* y   = u;    // fused kernel writes y in place over u

    // 0. convert x to bf16; transpose weights to bf16 B^T layouts
    f32_to_bf16_kernel<<<16384, 256, 0, stream>>>(x, xbf, (size_t)BL * DMODEL);
    transpose_to_bf16_kernel<<<dim3(128, 32), 256, 0, stream>>>(
        W_in, W_inT, DMODEL, 2 * DINNER, 2 * DINNER);
    transpose_to_bf16_kernel<<<dim3(12, 64), 256, 0, stream>>>(
        W_x, W_xT, DINNER, XDBLW, 384);
    transpose_to_bf16_kernel<<<dim3(32, 64), 256, 0, stream>>>(
        W_out, W_outT, DINNER, DMODEL, DMODEL);

    // 1a. zpre = x @ W_in[:, 2048:4096] → scr
    mfma_gemm<bf16><<<dim3(16, 128), 256, 0, stream>>>(
        xbf, W_inT + (size_t)DINNER * DMODEL, scr, BL, DINNER, DMODEL,
        DMODEL, DMODEL, DINNER);
    // 1b. z = silu(conv(zpre))
    conv_one_kernel<<<BL, 256, 0, stream>>>(scr, conv_zk, conv_zb, z);
    // 2a. upre = x @ W_in[:, 0:2048] → scr (zpre dead)
    mfma_gemm<bf16><<<dim3(16, 128), 256, 0, stream>>>(
        xbf, W_inT, scr, BL, DINNER, DMODEL, DMODEL, DMODEL, DINNER);
    // 2b. u = silu(conv(upre))  (overwrites xbf/W_inT region — both dead)
    conv_one_kernel<<<BL, 256, 0, stream>>>(scr, conv_xk, conv_xb, u);
    // 3. x_dbl = u @ W_x
    mfma_gemm<float><<<dim3(3, 128), 256, 0, stream>>>(
        u, W_xT, x_dbl, BL, XDBLW, DINNER, DINNER, DINNER, XDBLW);
    // 4. dt / dA cumsums
    dt_kernel<<<BATCH * NCHUNK * 8, 256, 0, stream>>>(
        x_dbl, dt_bias, A_log, dtb, dacs, ctot);
    // 5. SSD per group: states (MFMA, parallel) -> scan -> fused diag+off
    for (int g = 0; g < NGROUP; g++) {
        ssd_states_kernel<<<dim3(NHEADS, GC, BATCH), 256, 0, stream>>>(
            u, x_dbl, dtb, dacs, stG, g);
        ssd_scan_kernel<<<512, 256, 0, stream>>>(stG, ctot, runbuf, g);
        ssd_fused_kernel<<<dim3(NHEADS, GC, BATCH), 256, 0, stream>>>(
            u, x_dbl, dtb, dacs, Dv, stG, y, g);
    }
    // 6. gate + RMS norm (in place on y = u region)
    gate_norm_kernel<<<BL, 256, 0, stream>>>(y, z, norm_w);
    // 7. out = y @ W_out
    mfma_gemm<float><<<dim3(8, 128), 256, 0, stream>>>(
        y, W_outT, out, BL, DMODEL, DINNER, DINNER, DINNER, DMODEL);
}